// Round 1
// baseline (299.385 us; speedup 1.0000x reference)
//
#include <hip/hip_runtime.h>
#include <hip/hip_bf16.h>
#include <cstdint>
#include <cstddef>

#define DD 200
#define NN 20000
#define EE 320000
#define RRR 512
#define KP 256      // padded K for GEMM
#define NC 1200     // real GEMM output cols
#define NCP 1216    // padded cols (38*32)
#define NTILES 38
#define MTILES 625

typedef __attribute__((ext_vector_type(8))) short bf16x8;
typedef __attribute__((ext_vector_type(4))) float f32x4;

__device__ __forceinline__ float bf2f(unsigned short u) {
  union { unsigned int i; float f; } v; v.i = ((unsigned int)u) << 16; return v.f;
}
__device__ __forceinline__ unsigned short f2bf(float f) {
  unsigned int x = __float_as_uint(f);
  unsigned int r = (x + 0x7fffu + ((x >> 16) & 1u)) >> 16;   // RNE
  return (unsigned short)r;
}

// ---- K1: Wsq = W_s@wq, Wdq = W_d@wq, Wrq = W_r@wq  (each 200x200 fp32) ----
__global__ __launch_bounds__(256) void k_wprod(const float* __restrict__ wt, const float* __restrict__ wq,
                                               float* __restrict__ Wsq, float* __restrict__ Wdq,
                                               float* __restrict__ Wrq) {
  int b = blockIdx.x;          // 0..599
  int j = threadIdx.x;
  if (j >= DD) return;
  int srow; float* outp;
  if (b < 200)      { srow = b;             outp = Wsq + b * DD; }
  else if (b < 400) { srow = 400 + (b-200); outp = Wdq + (b-200) * DD; }
  else              { srow = 200 + (b-400); outp = Wrq + (b-400) * DD; }
  const float* wrow = wt + srow * DD;
  float s = 0.f;
  for (int i = 0; i < DD; ++i) s += wrow[i] * wq[i * DD + j];
  outp[j] = s;
}

// ---- K2: build Bt [NCP][KP] bf16; column pairing for interleaved NodeT ----
__global__ __launch_bounds__(256) void k_bt(const float* __restrict__ wt, const float* __restrict__ lw,
                                            const float* __restrict__ elw, const float* __restrict__ Wsq,
                                            const float* __restrict__ Wdq, unsigned short* __restrict__ Bt) {
  int j = blockIdx.x;          // 0..1215 output column
  int k = threadIdx.x;         // 0..255
  float val = 0.f;
  if (j < NC && k < DD) {
    int pair = j >> 1, bit = j & 1;
    int grp = pair / DD, jj = pair % DD;
    if (grp == 0)      val = bit ? Wsq[k * DD + jj] : wt[k * DD + jj];
    else if (grp == 1) val = bit ? Wdq[k * DD + jj] : wt[(2 * DD + k) * DD + jj];
    else               val = bit ? elw[k * DD + jj] : lw[k * DD + jj];
  }
  Bt[j * KP + k] = f2bf(val);
}

// ---- K3: node -> bf16, K padded to 256 ----
__global__ __launch_bounds__(256) void k_node(const float* __restrict__ node, unsigned short* __restrict__ A) {
  int n = blockIdx.x; int k = threadIdx.x;
  float v = (k < DD) ? node[n * DD + k] : 0.f;
  A[n * KP + k] = f2bf(v);
}

// ---- K4: cq[j] = colsum(w_quad) ----
__global__ void k_cq(const float* __restrict__ wq, float* __restrict__ cq) {
  int j = threadIdx.x;
  if (j >= DD) return;
  float s = 0.f;
  for (int i = 0; i < DD; ++i) s += wq[i * DD + j];
  cq[j] = s;
}

// ---- K5: bf16 MFMA GEMM: NodeT[m][j] = sum_k A[m][k]*Bt[j][k] ----
__global__ __launch_bounds__(256) void k_gemm(const unsigned short* __restrict__ A,
                                              const unsigned short* __restrict__ Bt,
                                              unsigned short* __restrict__ C) {
  int w = blockIdx.x * 4 + (threadIdx.x >> 6);
  if (w >= MTILES * NTILES) return;
  int mt = w / NTILES, nt = w % NTILES;
  int l = threadIdx.x & 63;
  int lr = l & 15;
  int lk = (l >> 4) * 8;
  int mbase = mt * 32, cbase = nt * 32;
  f32x4 acc[2][2] = {};
  const unsigned short* a0p = A + (size_t)(mbase + lr) * KP + lk;
  const unsigned short* a1p = A + (size_t)(mbase + 16 + lr) * KP + lk;
  const unsigned short* b0p = Bt + (size_t)(cbase + lr) * KP + lk;
  const unsigned short* b1p = Bt + (size_t)(cbase + 16 + lr) * KP + lk;
#pragma unroll
  for (int kk = 0; kk < KP; kk += 32) {
    bf16x8 a0 = *(const bf16x8*)(a0p + kk);
    bf16x8 a1 = *(const bf16x8*)(a1p + kk);
    bf16x8 b0 = *(const bf16x8*)(b0p + kk);
    bf16x8 b1 = *(const bf16x8*)(b1p + kk);
    acc[0][0] = __builtin_amdgcn_mfma_f32_16x16x32_bf16(a0, b0, acc[0][0], 0, 0, 0);
    acc[0][1] = __builtin_amdgcn_mfma_f32_16x16x32_bf16(a0, b1, acc[0][1], 0, 0, 0);
    acc[1][0] = __builtin_amdgcn_mfma_f32_16x16x32_bf16(a1, b0, acc[1][0], 0, 0, 0);
    acc[1][1] = __builtin_amdgcn_mfma_f32_16x16x32_bf16(a1, b1, acc[1][1], 0, 0, 0);
  }
  int rb = (l >> 4) * 4;
#pragma unroll
  for (int mi = 0; mi < 2; ++mi)
#pragma unroll
    for (int ni = 0; ni < 2; ++ni) {
      int col = cbase + ni * 16 + lr;
      if (col < NC) {
#pragma unroll
        for (int r = 0; r < 4; ++r) {
          int row = mbase + mi * 16 + rb + r;
          C[(size_t)row * NC + col] = f2bf(acc[mi][ni][r]);
        }
      }
    }
}

// ---- K6: RelT[r][2j]=RW, [2j+1]=RWq (fp32, interleaved) ----
__global__ __launch_bounds__(256) void k_rel(const float* __restrict__ rel, const float* __restrict__ wt,
                                             const float* __restrict__ Wrq, float* __restrict__ RelT) {
  int r = blockIdx.x; int j = threadIdx.x;
  if (j >= DD) return;
  const float* rrow = rel + r * DD;
  float s0 = 0.f, s1 = 0.f;
  for (int k = 0; k < DD; ++k) {
    float rv = rrow[k];
    s0 += rv * wt[(DD + k) * DD + j];
    s1 += rv * Wrq[k * DD + j];
  }
  RelT[r * 2 * DD + 2 * j]     = s0;
  RelT[r * 2 * DD + 2 * j + 1] = s1;
}

// ---- K7: degree histogram ----
__global__ __launch_bounds__(256) void k_deg(const int* __restrict__ dst, int* __restrict__ deg) {
  int e = blockIdx.x * 256 + threadIdx.x;
  if (e < EE) atomicAdd(&deg[dst[e]], 1);
}

// ---- K8: single-block exclusive scan over NN ----
__global__ __launch_bounds__(1024) void k_scan(const int* __restrict__ deg, int* __restrict__ offs) {
  __shared__ int buf[1024];
  __shared__ int carry_s;
  int tid = threadIdx.x;
  if (tid == 0) carry_s = 0;
  __syncthreads();
  for (int base = 0; base < NN; base += 1024) {
    int v = (base + tid < NN) ? deg[base + tid] : 0;
    buf[tid] = v;
    __syncthreads();
    for (int off = 1; off < 1024; off <<= 1) {
      int t = (tid >= off) ? buf[tid - off] : 0;
      __syncthreads();
      buf[tid] += t;
      __syncthreads();
    }
    int inc = buf[tid];
    int c = carry_s;
    if (base + tid < NN) offs[base + tid] = c + inc - v;
    __syncthreads();
    if (tid == 1023) carry_s = c + inc;
    __syncthreads();
  }
  if (tid == 0) offs[NN] = carry_s;
}

// ---- K9: scatter edges into CSR order ----
__global__ __launch_bounds__(256) void k_scatter(const int* __restrict__ src, const int* __restrict__ dst,
                                                 const int* __restrict__ typ, const float* __restrict__ fre,
                                                 const int* __restrict__ offs, int* __restrict__ cursor,
                                                 int* __restrict__ ssrc, int* __restrict__ styp,
                                                 float* __restrict__ sfre) {
  int e = blockIdx.x * 256 + threadIdx.x;
  if (e >= EE) return;
  int d = dst[e];
  int p = offs[d] + atomicAdd(&cursor[d], 1);
  ssrc[p] = src[e]; styp[p] = typ[e]; sfre[p] = fre[e];
}

// ---- K10: per-node online-softmax aggregation + loop + relu ----
__global__ __launch_bounds__(256) void k_agg(const unsigned int* __restrict__ NodeTu,  // [NN][600] u32 pairs
                                             const float* __restrict__ RelT,
                                             const float* __restrict__ cq,
                                             const float* __restrict__ norm,
                                             const int* __restrict__ offs,
                                             const int* __restrict__ ssrc, const int* __restrict__ styp,
                                             const float* __restrict__ sfre,
                                             float* __restrict__ out) {
  int n = blockIdx.x;
  int j = threadIdx.x;
  if (j >= DD) return;
  int e0 = offs[n], e1 = offs[n + 1];
  unsigned int dpair = NodeTu[(size_t)n * 600 + 200 + j];
  float xd  = bf2f((unsigned short)(dpair & 0xffffu));
  float xdq = bf2f((unsigned short)(dpair >> 16));
  float cqj = cq[j];
  float m = -INFINITY, s = 0.f, num = 0.f;
  for (int i = e0; i < e1; ++i) {
    int srcn = ssrc[i];
    int rt   = styp[i];
    float f  = sfre[i];
    unsigned int spair = NodeTu[(size_t)srcn * 600 + j];
    const float2 rp = *reinterpret_cast<const float2*>(RelT + (size_t)rt * (2 * DD) + 2 * j);
    float t  = bf2f((unsigned short)(spair & 0xffffu)) + rp.x + xd;
    float aq = bf2f((unsigned short)(spair >> 16)) + rp.y + xdq + f * cqj;
    float a  = (aq > 0.f) ? aq : 0.01f * aq;
    float nm = fmaxf(m, a);
    float sc = __expf(m - nm);
    float ea = __expf(a - nm);
    s   = s * sc + ea;
    num = num * sc + ea * t;
    m = nm;
  }
  unsigned int lpair = NodeTu[(size_t)n * 600 + 400 + j];
  float h = 0.f, lm;
  if (e1 > e0) {
    h  = (num / s) * norm[n];
    lm = bf2f((unsigned short)(lpair & 0xffffu));
  } else {
    lm = bf2f((unsigned short)(lpair >> 16));
  }
  float o = h + lm;
  out[(size_t)n * DD + j] = o > 0.f ? o : 0.f;
}

extern "C" void kernel_launch(void* const* d_in, const int* in_sizes, int n_in,
                              void* d_out, int out_size, void* d_ws, size_t ws_size,
                              hipStream_t stream) {
  const float* node = (const float*)d_in[0];
  const float* rel  = (const float*)d_in[1];
  const float* norm = (const float*)d_in[2];
  const float* fre  = (const float*)d_in[3];
  const float* wt   = (const float*)d_in[4];
  const float* wq   = (const float*)d_in[5];
  const float* lw   = (const float*)d_in[6];
  const float* elw  = (const float*)d_in[7];
  const int* esrc = (const int*)d_in[8];
  const int* edst = (const int*)d_in[9];
  const int* etyp = (const int*)d_in[10];
  float* out = (float*)d_out;

  char* p = (char*)d_ws;
  auto carve = [&](size_t bytes) -> char* {
    char* r = p; p += (bytes + 255) & ~(size_t)255; return r;
  };
  unsigned short* A     = (unsigned short*)carve((size_t)NN * KP * 2);
  unsigned short* Bt    = (unsigned short*)carve((size_t)NCP * KP * 2);
  unsigned short* NodeT = (unsigned short*)carve((size_t)NN * NC * 2);
  float* RelT = (float*)carve((size_t)RRR * 2 * DD * 4);
  float* Wsq  = (float*)carve((size_t)DD * DD * 4);
  float* Wdq  = (float*)carve((size_t)DD * DD * 4);
  float* Wrq  = (float*)carve((size_t)DD * DD * 4);
  float* cq   = (float*)carve((size_t)DD * 4);
  int* deg    = (int*)carve((size_t)NN * 4);
  int* offs   = (int*)carve((size_t)(NN + 1) * 4);
  int* cursor = (int*)carve((size_t)NN * 4);
  int* ssrc   = (int*)carve((size_t)EE * 4);
  int* styp   = (int*)carve((size_t)EE * 4);
  float* sfre = (float*)carve((size_t)EE * 4);

  hipMemsetAsync(deg, 0, (size_t)NN * 4, stream);
  hipMemsetAsync(cursor, 0, (size_t)NN * 4, stream);

  k_wprod<<<600, 256, 0, stream>>>(wt, wq, Wsq, Wdq, Wrq);
  k_bt<<<NCP, 256, 0, stream>>>(wt, lw, elw, Wsq, Wdq, Bt);
  k_node<<<NN, 256, 0, stream>>>(node, A);
  k_cq<<<1, 256, 0, stream>>>(wq, cq);
  k_rel<<<RRR, 256, 0, stream>>>(rel, wt, Wrq, RelT);
  k_gemm<<<(MTILES * NTILES + 3) / 4, 256, 0, stream>>>(A, Bt, NodeT);
  k_deg<<<(EE + 255) / 256, 256, 0, stream>>>(edst, deg);
  k_scan<<<1, 1024, 0, stream>>>(deg, offs);
  k_scatter<<<(EE + 255) / 256, 256, 0, stream>>>(esrc, edst, etyp, fre, offs, cursor,
                                                  ssrc, styp, sfre);
  k_agg<<<NN, 256, 0, stream>>>((const unsigned int*)NodeT, RelT, cq, norm, offs,
                                ssrc, styp, sfre, out);
}

// Round 2
// 195.459 us; speedup vs baseline: 1.5317x; 1.5317x over previous
//
#include <hip/hip_runtime.h>
#include <hip/hip_bf16.h>
#include <cstdint>
#include <cstddef>

#define DD 200
#define NN 20000
#define EE 320000
#define RRR 512
#define KP 256      // padded K
#define MP 20096    // 157*128 padded rows
#define NCP 1280    // 10*128 padded cols (1200 real)
#define MT 157
#define NT 10

typedef __attribute__((ext_vector_type(8))) short bf16x8;
typedef __attribute__((ext_vector_type(4))) float f32x4;

__device__ __forceinline__ float bf2f(unsigned short u) {
  union { unsigned int i; float f; } v; v.i = ((unsigned int)u) << 16; return v.f;
}
__device__ __forceinline__ unsigned short f2bf(float f) {
  unsigned int x = __float_as_uint(f);
  unsigned int r = (x + 0x7fffu + ((x >> 16) & 1u)) >> 16;   // RNE
  return (unsigned short)r;
}
__device__ __forceinline__ void gl_lds16(const unsigned short* g, unsigned short* l) {
  __builtin_amdgcn_global_load_lds(
      (const __attribute__((address_space(1))) void*)g,
      (__attribute__((address_space(3))) void*)l, 16, 0, 0);
}

// ---- K1: Wsq = W_s@wq, Wdq = W_d@wq, Wrq = W_r@wq; block 600 does cq ----
__global__ __launch_bounds__(256) void k_wprod(const float* __restrict__ wt, const float* __restrict__ wq,
                                               float* __restrict__ Wsq, float* __restrict__ Wdq,
                                               float* __restrict__ Wrq, float* __restrict__ cq) {
  int b = blockIdx.x;          // 0..600
  int j = threadIdx.x;
  if (j >= DD) return;
  if (b == 600) {              // cq[j] = colsum(w_quad)
    float s = 0.f;
    for (int i = 0; i < DD; ++i) s += wq[i * DD + j];
    cq[j] = s;
    return;
  }
  int srow; float* outp;
  if (b < 200)      { srow = b;             outp = Wsq + b * DD; }
  else if (b < 400) { srow = 400 + (b-200); outp = Wdq + (b-200) * DD; }
  else              { srow = 200 + (b-400); outp = Wrq + (b-400) * DD; }
  const float* wrow = wt + srow * DD;
  float s = 0.f;
  for (int i = 0; i < DD; ++i) s += wrow[i] * wq[i * DD + j];
  outp[j] = s;
}

// ---- K2: Bt [NCP][KP] bf16. col c: g=c/400 (0:S,1:D,2:loop), w=c%400, j=w>>1, bit=w&1 ----
__global__ __launch_bounds__(256) void k_bt(const float* __restrict__ wt, const float* __restrict__ lw,
                                            const float* __restrict__ elw, const float* __restrict__ Wsq,
                                            const float* __restrict__ Wdq, unsigned short* __restrict__ Bt) {
  int c = blockIdx.x;          // 0..1279
  int k = threadIdx.x;         // 0..255
  float val = 0.f;
  if (c < 1200 && k < DD) {
    int g = c / 400, w = c % 400, j = w >> 1, bit = w & 1;
    if (g == 0)      val = bit ? Wsq[k * DD + j] : wt[k * DD + j];
    else if (g == 1) val = bit ? Wdq[k * DD + j] : wt[(2 * DD + k) * DD + j];
    else             val = bit ? elw[k * DD + j] : lw[k * DD + j];
  }
  Bt[(size_t)c * KP + k] = f2bf(val);
}

// ---- K3: node -> bf16 A, K padded ----
__global__ __launch_bounds__(256) void k_node(const float* __restrict__ node, unsigned short* __restrict__ A) {
  int n = blockIdx.x; int k = threadIdx.x;
  float v = (k < DD) ? node[(size_t)n * DD + k] : 0.f;
  A[(size_t)n * KP + k] = f2bf(v);
}

// ---- K5: 128x128 LDS-staged MFMA GEMM with XOR-swizzled staging ----
__global__ __launch_bounds__(256) void k_gemm(const unsigned short* __restrict__ A,
                                              const unsigned short* __restrict__ Bt,
                                              unsigned short* __restrict__ NT2) {
  __shared__ unsigned short As[128 * 32];
  __shared__ unsigned short Bs[128 * 32];
  int bid = blockIdx.x;
  int mt = bid / NT, nt = bid % NT;
  int t = threadIdx.x, lane = t & 63, wv = t >> 6;
  int lr = lane & 15, k8 = lane >> 4;          // fragment coords
  int wm = (wv >> 1) * 64, wn = (wv & 1) * 64; // wave's 64x64 quadrant
  int sr = wv * 16 + (lane >> 2);              // staging row within 64-half
  int sc = lane & 3;                           // staging physical chunk
  f32x4 acc[4][4] = {};
  const unsigned short* Ag = A + (size_t)(mt * 128) * KP;
  const unsigned short* Bg = Bt + (size_t)(nt * 128) * KP;
  for (int kk = 0; kk < KP; kk += 32) {
#pragma unroll
    for (int i = 0; i < 2; ++i) {
      int row = i * 64 + sr;
      int gcol = kk + ((sc ^ (row & 3)) << 3);     // pre-swizzled source
      unsigned short* ldst = (i * 2048 + wv * 512) + (unsigned short*)0;
      gl_lds16(Ag + (size_t)row * KP + gcol, As + i * 2048 + wv * 512);
      gl_lds16(Bg + (size_t)row * KP + gcol, Bs + i * 2048 + wv * 512);
      (void)ldst;
    }
    __syncthreads();   // vmcnt(0)+lgkmcnt drain then barrier
    bf16x8 af[4], bfr[4];
#pragma unroll
    for (int mi = 0; mi < 4; ++mi) {
      int row = wm + mi * 16 + lr;
      af[mi] = *(const bf16x8*)(As + row * 32 + ((k8 ^ (row & 3)) << 3));
      int col = wn + mi * 16 + lr;
      bfr[mi] = *(const bf16x8*)(Bs + col * 32 + ((k8 ^ (col & 3)) << 3));
    }
#pragma unroll
    for (int mi = 0; mi < 4; ++mi)
#pragma unroll
      for (int ni = 0; ni < 4; ++ni)
        acc[mi][ni] = __builtin_amdgcn_mfma_f32_16x16x32_bf16(af[mi], bfr[ni], acc[mi][ni], 0, 0, 0);
    __syncthreads();
  }
  int rb = k8 * 4;
#pragma unroll
  for (int mi = 0; mi < 4; ++mi)
#pragma unroll
    for (int ni = 0; ni < 4; ++ni) {
      int col = nt * 128 + wn + ni * 16 + lr;
      if (col < 1200) {
        int g = col / 400, w = col % 400;
        unsigned short* dst = NT2 + (size_t)g * NN * 400 + w;
#pragma unroll
        for (int r = 0; r < 4; ++r) {
          int row = mt * 128 + wm + mi * 16 + rb + r;
          if (row < NN) dst[(size_t)row * 400] = f2bf(acc[mi][ni][r]);
        }
      }
    }
}

// ---- K6: RelT[r][2j]=RW, [2j+1]=RWq (fp32) ----
__global__ __launch_bounds__(256) void k_rel(const float* __restrict__ rel, const float* __restrict__ wt,
                                             const float* __restrict__ Wrq, float* __restrict__ RelT) {
  int r = blockIdx.x; int j = threadIdx.x;
  if (j >= DD) return;
  const float* rrow = rel + (size_t)r * DD;
  float s0 = 0.f, s1 = 0.f;
  for (int k = 0; k < DD; ++k) {
    float rv = rrow[k];
    s0 += rv * wt[(DD + k) * DD + j];
    s1 += rv * Wrq[k * DD + j];
  }
  RelT[(size_t)r * 400 + 2 * j]     = s0;
  RelT[(size_t)r * 400 + 2 * j + 1] = s1;
}

// ---- K7: degree histogram ----
__global__ __launch_bounds__(256) void k_deg(const int* __restrict__ dst, int* __restrict__ deg) {
  int e = blockIdx.x * 256 + threadIdx.x;
  if (e < EE) atomicAdd(&deg[dst[e]], 1);
}

// ---- K8: single-block shuffle-based exclusive scan ----
__global__ __launch_bounds__(1024) void k_scan(const int* __restrict__ deg, int* __restrict__ offs) {
  __shared__ int wsum[16];
  __shared__ int carry_s;
  int tid = threadIdx.x, lane = tid & 63, wv = tid >> 6;
  if (tid == 0) carry_s = 0;
  __syncthreads();
  for (int base = 0; base < NN; base += 1024) {
    int idx = base + tid;
    int v = (idx < NN) ? deg[idx] : 0;
    int x = v;
#pragma unroll
    for (int off = 1; off < 64; off <<= 1) {
      int y = __shfl_up(x, off, 64);
      if (lane >= off) x += y;
    }
    if (lane == 63) wsum[wv] = x;
    __syncthreads();
    if (wv == 0) {
      int w = (lane < 16) ? wsum[lane] : 0;
#pragma unroll
      for (int off = 1; off < 16; off <<= 1) {
        int y = __shfl_up(w, off, 64);
        if (lane >= off) w += y;
      }
      if (lane < 16) wsum[lane] = w;
    }
    __syncthreads();
    int wpre = (wv == 0) ? 0 : wsum[wv - 1];
    int c = carry_s;
    if (idx < NN) offs[idx] = c + wpre + x - v;
    __syncthreads();
    if (tid == 1023) carry_s = c + wsum[15];
    __syncthreads();
  }
  if (threadIdx.x == 0) offs[NN] = carry_s;
}

// ---- K9: scatter edges into CSR order; pack src|typ<<15 ----
__global__ __launch_bounds__(256) void k_scatter(const int* __restrict__ src, const int* __restrict__ dst,
                                                 const int* __restrict__ typ, const float* __restrict__ fre,
                                                 const int* __restrict__ offs, int* __restrict__ cursor,
                                                 int* __restrict__ spk, float* __restrict__ sfre) {
  int e = blockIdx.x * 256 + threadIdx.x;
  if (e >= EE) return;
  int d = dst[e];
  int p = offs[d] + atomicAdd(&cursor[d], 1);
  spk[p] = src[e] | (typ[e] << 15);
  sfre[p] = fre[e];
}

// ---- K10: per-node aggregation (direct exp), 2-edge pipelined ----
__global__ __launch_bounds__(256) void k_agg(const unsigned int* __restrict__ GSu,
                                             const unsigned int* __restrict__ GDu,
                                             const unsigned int* __restrict__ GLu,
                                             const float* __restrict__ RelT,
                                             const float* __restrict__ cq,
                                             const float* __restrict__ norm,
                                             const int* __restrict__ offs,
                                             const int* __restrict__ spk, const float* __restrict__ sfre,
                                             float* __restrict__ out) {
  int n = blockIdx.x;
  int j = threadIdx.x;
  if (j >= DD) return;
  int e0 = offs[n], e1 = offs[n + 1];
  unsigned dp = GDu[(size_t)n * 200 + j];
  float xd  = bf2f((unsigned short)(dp & 0xffffu));
  float xdq = bf2f((unsigned short)(dp >> 16));
  float cqj = cq[j];
  float s = 0.f, num = 0.f;
  int i = e0;
  for (; i + 2 <= e1; i += 2) {
    int p0 = spk[i], p1 = spk[i + 1];
    float f0 = sfre[i], f1 = sfre[i + 1];
    unsigned sp0 = GSu[(size_t)(p0 & 0x7fff) * 200 + j];
    float2 r0 = *(const float2*)(RelT + (size_t)((unsigned)p0 >> 15) * 400 + 2 * j);
    unsigned sp1 = GSu[(size_t)(p1 & 0x7fff) * 200 + j];
    float2 r1 = *(const float2*)(RelT + (size_t)((unsigned)p1 >> 15) * 400 + 2 * j);
    float t0  = bf2f((unsigned short)(sp0 & 0xffffu)) + r0.x + xd;
    float aq0 = bf2f((unsigned short)(sp0 >> 16)) + r0.y + xdq + f0 * cqj;
    float a0  = (aq0 > 0.f) ? aq0 : 0.01f * aq0;
    float ev0 = __expf(a0);
    float t1  = bf2f((unsigned short)(sp1 & 0xffffu)) + r1.x + xd;
    float aq1 = bf2f((unsigned short)(sp1 >> 16)) + r1.y + xdq + f1 * cqj;
    float a1  = (aq1 > 0.f) ? aq1 : 0.01f * aq1;
    float ev1 = __expf(a1);
    s   += ev0 + ev1;
    num += ev0 * t0 + ev1 * t1;
  }
  if (i < e1) {
    int p0 = spk[i]; float f0 = sfre[i];
    unsigned sp0 = GSu[(size_t)(p0 & 0x7fff) * 200 + j];
    float2 r0 = *(const float2*)(RelT + (size_t)((unsigned)p0 >> 15) * 400 + 2 * j);
    float t0  = bf2f((unsigned short)(sp0 & 0xffffu)) + r0.x + xd;
    float aq0 = bf2f((unsigned short)(sp0 >> 16)) + r0.y + xdq + f0 * cqj;
    float a0  = (aq0 > 0.f) ? aq0 : 0.01f * aq0;
    float ev0 = __expf(a0);
    s += ev0; num += ev0 * t0;
  }
  unsigned lp = GLu[(size_t)n * 200 + j];
  float o;
  if (e1 > e0) o = (num / s) * norm[n] + bf2f((unsigned short)(lp & 0xffffu));
  else         o = bf2f((unsigned short)(lp >> 16));
  out[(size_t)n * DD + j] = fmaxf(o, 0.f);
}

extern "C" void kernel_launch(void* const* d_in, const int* in_sizes, int n_in,
                              void* d_out, int out_size, void* d_ws, size_t ws_size,
                              hipStream_t stream) {
  const float* node = (const float*)d_in[0];
  const float* rel  = (const float*)d_in[1];
  const float* norm = (const float*)d_in[2];
  const float* fre  = (const float*)d_in[3];
  const float* wt   = (const float*)d_in[4];
  const float* wq   = (const float*)d_in[5];
  const float* lw   = (const float*)d_in[6];
  const float* elw  = (const float*)d_in[7];
  const int* esrc = (const int*)d_in[8];
  const int* edst = (const int*)d_in[9];
  const int* etyp = (const int*)d_in[10];
  float* out = (float*)d_out;

  char* p = (char*)d_ws;
  auto carve = [&](size_t bytes) -> char* {
    char* r = p; p += (bytes + 255) & ~(size_t)255; return r;
  };
  unsigned short* A   = (unsigned short*)carve((size_t)MP * KP * 2);
  unsigned short* Bt  = (unsigned short*)carve((size_t)NCP * KP * 2);
  unsigned short* NT2 = (unsigned short*)carve((size_t)3 * NN * 400 * 2);
  float* RelT = (float*)carve((size_t)RRR * 400 * 4);
  float* Wsq  = (float*)carve((size_t)DD * DD * 4);
  float* Wdq  = (float*)carve((size_t)DD * DD * 4);
  float* Wrq  = (float*)carve((size_t)DD * DD * 4);
  float* cq   = (float*)carve((size_t)DD * 4);
  int* deg    = (int*)carve((size_t)NN * 4);
  int* offs   = (int*)carve((size_t)(NN + 1) * 4);
  int* cursor = (int*)carve((size_t)NN * 4);
  int* spk    = (int*)carve((size_t)EE * 4);
  float* sfre = (float*)carve((size_t)EE * 4);

  const unsigned int* GSu = (const unsigned int*)NT2;
  const unsigned int* GDu = GSu + (size_t)NN * 200;
  const unsigned int* GLu = GSu + (size_t)2 * NN * 200;

  hipMemsetAsync(deg, 0, (size_t)NN * 4, stream);
  hipMemsetAsync(cursor, 0, (size_t)NN * 4, stream);

  k_wprod<<<601, 256, 0, stream>>>(wt, wq, Wsq, Wdq, Wrq, cq);
  k_node<<<NN, 256, 0, stream>>>(node, A);
  k_deg<<<(EE + 255) / 256, 256, 0, stream>>>(edst, deg);
  k_bt<<<NCP, 256, 0, stream>>>(wt, lw, elw, Wsq, Wdq, Bt);
  k_rel<<<RRR, 256, 0, stream>>>(rel, wt, Wrq, RelT);
  k_scan<<<1, 1024, 0, stream>>>(deg, offs);
  k_gemm<<<MT * NT, 256, 0, stream>>>(A, Bt, NT2);
  k_scatter<<<(EE + 255) / 256, 256, 0, stream>>>(esrc, edst, etyp, fre, offs, cursor,
                                                  spk, sfre);
  k_agg<<<NN, 256, 0, stream>>>(GSu, GDu, GLu, RelT, cq, norm, offs, spk, sfre, out);
}

// Round 3
// 178.665 us; speedup vs baseline: 1.6757x; 1.0940x over previous
//
#include <hip/hip_runtime.h>
#include <hip/hip_bf16.h>
#include <cstdint>
#include <cstddef>

#define DD 200
#define NN 20000
#define EE 320000
#define RRR 512
#define KP 256      // padded K
#define MP 20096    // 157*128 padded rows
#define NCP 1280    // 10*128 padded cols (1200 real)
#define MT 157
#define NT 10

typedef __attribute__((ext_vector_type(8))) short bf16x8;
typedef __attribute__((ext_vector_type(4))) float f32x4;

__device__ __forceinline__ float bf2f_lo(unsigned int u) {
  return __uint_as_float(u << 16);
}
__device__ __forceinline__ float bf2f_hi(unsigned int u) {
  return __uint_as_float(u & 0xffff0000u);
}
__device__ __forceinline__ unsigned short f2bf(float f) {
  unsigned int x = __float_as_uint(f);
  unsigned int r = (x + 0x7fffu + ((x >> 16) & 1u)) >> 16;   // RNE
  return (unsigned short)r;
}
__device__ __forceinline__ void gl_lds16(const unsigned short* g, unsigned short* l) {
  __builtin_amdgcn_global_load_lds(
      (const __attribute__((address_space(1))) void*)g,
      (__attribute__((address_space(3))) void*)l, 16, 0, 0);
}

// ---- K1: Wsq = W_s@wq, Wdq = W_d@wq, Wrq = W_r@wq; block 600 does cq ----
__global__ __launch_bounds__(256) void k_wprod(const float* __restrict__ wt, const float* __restrict__ wq,
                                               float* __restrict__ Wsq, float* __restrict__ Wdq,
                                               float* __restrict__ Wrq, float* __restrict__ cq) {
  int b = blockIdx.x;          // 0..600
  int j = threadIdx.x;
  if (j >= DD) return;
  if (b == 600) {              // cq[j] = colsum(w_quad)
    float s = 0.f;
    for (int i = 0; i < DD; ++i) s += wq[i * DD + j];
    cq[j] = s;
    return;
  }
  int srow; float* outp;
  if (b < 200)      { srow = b;             outp = Wsq + b * DD; }
  else if (b < 400) { srow = 400 + (b-200); outp = Wdq + (b-200) * DD; }
  else              { srow = 200 + (b-400); outp = Wrq + (b-400) * DD; }
  const float* wrow = wt + srow * DD;
  float s = 0.f;
  for (int i = 0; i < DD; ++i) s += wrow[i] * wq[i * DD + j];
  outp[j] = s;
}

// ---- K2: Bt [NCP][KP] bf16. col c: g=c/400 (0:S,1:D,2:loop), w=c%400, j=w>>1, bit=w&1 ----
__global__ __launch_bounds__(256) void k_bt(const float* __restrict__ wt, const float* __restrict__ lw,
                                            const float* __restrict__ elw, const float* __restrict__ Wsq,
                                            const float* __restrict__ Wdq, unsigned short* __restrict__ Bt) {
  int c = blockIdx.x;          // 0..1279
  int k = threadIdx.x;         // 0..255
  float val = 0.f;
  if (c < 1200 && k < DD) {
    int g = c / 400, w = c % 400, j = w >> 1, bit = w & 1;
    if (g == 0)      val = bit ? Wsq[k * DD + j] : wt[k * DD + j];
    else if (g == 1) val = bit ? Wdq[k * DD + j] : wt[(2 * DD + k) * DD + j];
    else             val = bit ? elw[k * DD + j] : lw[k * DD + j];
  }
  Bt[(size_t)c * KP + k] = f2bf(val);
}

// ---- K3: fused node->bf16 conversion (blocks 0..NN-1) + degree histogram ----
__global__ __launch_bounds__(256) void k_node_deg(const float* __restrict__ node, unsigned short* __restrict__ A,
                                                  const int* __restrict__ dst, int* __restrict__ deg) {
  int b = blockIdx.x;
  if (b < NN) {
    int k = threadIdx.x;
    float v = (k < DD) ? node[(size_t)b * DD + k] : 0.f;
    A[(size_t)b * KP + k] = f2bf(v);
  } else {
    int e = (b - NN) * 256 + threadIdx.x;
    if (e < EE) atomicAdd(&deg[dst[e]], 1);
  }
}

// ---- K5: 128x128 LDS-staged MFMA GEMM with XOR-swizzled staging ----
__global__ __launch_bounds__(256) void k_gemm(const unsigned short* __restrict__ A,
                                              const unsigned short* __restrict__ Bt,
                                              unsigned short* __restrict__ NT2) {
  __shared__ unsigned short As[128 * 32];
  __shared__ unsigned short Bs[128 * 32];
  int bid = blockIdx.x;
  int mt = bid / NT, nt = bid % NT;
  int t = threadIdx.x, lane = t & 63, wv = t >> 6;
  int lr = lane & 15, k8 = lane >> 4;          // fragment coords
  int wm = (wv >> 1) * 64, wn = (wv & 1) * 64; // wave's 64x64 quadrant
  int sr = wv * 16 + (lane >> 2);              // staging row within 64-half
  int sc = lane & 3;                           // staging physical chunk
  f32x4 acc[4][4] = {};
  const unsigned short* Ag = A + (size_t)(mt * 128) * KP;
  const unsigned short* Bg = Bt + (size_t)(nt * 128) * KP;
  for (int kk = 0; kk < KP; kk += 32) {
#pragma unroll
    for (int i = 0; i < 2; ++i) {
      int row = i * 64 + sr;
      int gcol = kk + ((sc ^ (row & 3)) << 3);     // pre-swizzled source
      gl_lds16(Ag + (size_t)row * KP + gcol, As + i * 2048 + wv * 512);
      gl_lds16(Bg + (size_t)row * KP + gcol, Bs + i * 2048 + wv * 512);
    }
    __syncthreads();
    bf16x8 af[4], bfr[4];
#pragma unroll
    for (int mi = 0; mi < 4; ++mi) {
      int row = wm + mi * 16 + lr;
      af[mi] = *(const bf16x8*)(As + row * 32 + ((k8 ^ (row & 3)) << 3));
      int col = wn + mi * 16 + lr;
      bfr[mi] = *(const bf16x8*)(Bs + col * 32 + ((k8 ^ (col & 3)) << 3));
    }
#pragma unroll
    for (int mi = 0; mi < 4; ++mi)
#pragma unroll
      for (int ni = 0; ni < 4; ++ni)
        acc[mi][ni] = __builtin_amdgcn_mfma_f32_16x16x32_bf16(af[mi], bfr[ni], acc[mi][ni], 0, 0, 0);
    __syncthreads();
  }
  int rb = k8 * 4;
#pragma unroll
  for (int mi = 0; mi < 4; ++mi)
#pragma unroll
    for (int ni = 0; ni < 4; ++ni) {
      int col = nt * 128 + wn + ni * 16 + lr;
      if (col < 1200) {
        int g = col / 400, w = col % 400;
        unsigned short* dst = NT2 + (size_t)g * NN * 400 + w;
#pragma unroll
        for (int r = 0; r < 4; ++r) {
          int row = mt * 128 + wm + mi * 16 + rb + r;
          if (row < NN) dst[(size_t)row * 400] = f2bf(acc[mi][ni][r]);
        }
      }
    }
}

// ---- K6: RelP[r][j] = pack(bf16(RW), bf16(RWq)) ----
__global__ __launch_bounds__(256) void k_rel(const float* __restrict__ rel, const float* __restrict__ wt,
                                             const float* __restrict__ Wrq, unsigned int* __restrict__ RelP) {
  int r = blockIdx.x; int j = threadIdx.x;
  if (j >= DD) return;
  const float* rrow = rel + (size_t)r * DD;
  float s0 = 0.f, s1 = 0.f;
  for (int k = 0; k < DD; ++k) {
    float rv = rrow[k];
    s0 += rv * wt[(DD + k) * DD + j];
    s1 += rv * Wrq[k * DD + j];
  }
  RelP[(size_t)r * DD + j] = (unsigned int)f2bf(s0) | ((unsigned int)f2bf(s1) << 16);
}

// ---- K8: single-block shuffle-based exclusive scan ----
__global__ __launch_bounds__(1024) void k_scan(const int* __restrict__ deg, int* __restrict__ offs) {
  __shared__ int wsum[16];
  __shared__ int carry_s;
  int tid = threadIdx.x, lane = tid & 63, wv = tid >> 6;
  if (tid == 0) carry_s = 0;
  __syncthreads();
  for (int base = 0; base < NN; base += 1024) {
    int idx = base + tid;
    int v = (idx < NN) ? deg[idx] : 0;
    int x = v;
#pragma unroll
    for (int off = 1; off < 64; off <<= 1) {
      int y = __shfl_up(x, off, 64);
      if (lane >= off) x += y;
    }
    if (lane == 63) wsum[wv] = x;
    __syncthreads();
    if (wv == 0) {
      int w = (lane < 16) ? wsum[lane] : 0;
#pragma unroll
      for (int off = 1; off < 16; off <<= 1) {
        int y = __shfl_up(w, off, 64);
        if (lane >= off) w += y;
      }
      if (lane < 16) wsum[lane] = w;
    }
    __syncthreads();
    int wpre = (wv == 0) ? 0 : wsum[wv - 1];
    int c = carry_s;
    if (idx < NN) offs[idx] = c + wpre + x - v;
    __syncthreads();
    if (tid == 1023) carry_s = c + wsum[15];
    __syncthreads();
  }
  if (threadIdx.x == 0) offs[NN] = carry_s;
}

// ---- K9: scatter edges into CSR order; pack src|typ<<15 ----
__global__ __launch_bounds__(256) void k_scatter(const int* __restrict__ src, const int* __restrict__ dst,
                                                 const int* __restrict__ typ, const float* __restrict__ fre,
                                                 const int* __restrict__ offs, int* __restrict__ cursor,
                                                 int* __restrict__ spk, float* __restrict__ sfre) {
  int e = blockIdx.x * 256 + threadIdx.x;
  if (e >= EE) return;
  int d = dst[e];
  int p = offs[d] + atomicAdd(&cursor[d], 1);
  spk[p] = src[e] | (typ[e] << 15);
  sfre[p] = fre[e];
}

// ---- K10: per-node aggregation, 4-edge batched gathers ----
__global__ __launch_bounds__(256) void k_agg(const unsigned int* __restrict__ GSu,
                                             const unsigned int* __restrict__ GDu,
                                             const unsigned int* __restrict__ GLu,
                                             const unsigned int* __restrict__ RelP,
                                             const float* __restrict__ cq,
                                             const float* __restrict__ norm,
                                             const int* __restrict__ offs,
                                             const int* __restrict__ spk, const float* __restrict__ sfre,
                                             float* __restrict__ out) {
  int n = blockIdx.x;
  int j = threadIdx.x;
  if (j >= DD) return;
  int e0 = offs[n], e1 = offs[n + 1];
  unsigned dp = GDu[(size_t)n * DD + j];
  float xd  = bf2f_lo(dp);
  float xdq = bf2f_hi(dp);
  float cqj = cq[j];
  float s = 0.f, num = 0.f;
  int i = e0;
  for (; i + 4 <= e1; i += 4) {
    int p0 = spk[i], p1 = spk[i+1], p2 = spk[i+2], p3 = spk[i+3];
    float f0 = sfre[i], f1 = sfre[i+1], f2 = sfre[i+2], f3 = sfre[i+3];
    unsigned sp0 = GSu[(unsigned)(p0 & 0x7fff) * DD + j];
    unsigned sp1 = GSu[(unsigned)(p1 & 0x7fff) * DD + j];
    unsigned sp2 = GSu[(unsigned)(p2 & 0x7fff) * DD + j];
    unsigned sp3 = GSu[(unsigned)(p3 & 0x7fff) * DD + j];
    unsigned rp0 = RelP[((unsigned)p0 >> 15) * DD + j];
    unsigned rp1 = RelP[((unsigned)p1 >> 15) * DD + j];
    unsigned rp2 = RelP[((unsigned)p2 >> 15) * DD + j];
    unsigned rp3 = RelP[((unsigned)p3 >> 15) * DD + j];
    float t0  = bf2f_lo(sp0) + bf2f_lo(rp0) + xd;
    float aq0 = bf2f_hi(sp0) + bf2f_hi(rp0) + fmaf(f0, cqj, xdq);
    float a0  = fmaxf(aq0, 0.01f * aq0);
    float ev0 = __expf(a0);
    float t1  = bf2f_lo(sp1) + bf2f_lo(rp1) + xd;
    float aq1 = bf2f_hi(sp1) + bf2f_hi(rp1) + fmaf(f1, cqj, xdq);
    float a1  = fmaxf(aq1, 0.01f * aq1);
    float ev1 = __expf(a1);
    float t2  = bf2f_lo(sp2) + bf2f_lo(rp2) + xd;
    float aq2 = bf2f_hi(sp2) + bf2f_hi(rp2) + fmaf(f2, cqj, xdq);
    float a2  = fmaxf(aq2, 0.01f * aq2);
    float ev2 = __expf(a2);
    float t3  = bf2f_lo(sp3) + bf2f_lo(rp3) + xd;
    float aq3 = bf2f_hi(sp3) + bf2f_hi(rp3) + fmaf(f3, cqj, xdq);
    float a3  = fmaxf(aq3, 0.01f * aq3);
    float ev3 = __expf(a3);
    s   += (ev0 + ev1) + (ev2 + ev3);
    num = fmaf(ev0, t0, num);
    num = fmaf(ev1, t1, num);
    num = fmaf(ev2, t2, num);
    num = fmaf(ev3, t3, num);
  }
  for (; i < e1; ++i) {
    int p0 = spk[i]; float f0 = sfre[i];
    unsigned sp0 = GSu[(unsigned)(p0 & 0x7fff) * DD + j];
    unsigned rp0 = RelP[((unsigned)p0 >> 15) * DD + j];
    float t0  = bf2f_lo(sp0) + bf2f_lo(rp0) + xd;
    float aq0 = bf2f_hi(sp0) + bf2f_hi(rp0) + fmaf(f0, cqj, xdq);
    float a0  = fmaxf(aq0, 0.01f * aq0);
    float ev0 = __expf(a0);
    s += ev0;
    num = fmaf(ev0, t0, num);
  }
  unsigned lp = GLu[(size_t)n * DD + j];
  float o;
  if (e1 > e0) o = (num / s) * norm[n] + bf2f_lo(lp);
  else         o = bf2f_hi(lp);
  out[(size_t)n * DD + j] = fmaxf(o, 0.f);
}

extern "C" void kernel_launch(void* const* d_in, const int* in_sizes, int n_in,
                              void* d_out, int out_size, void* d_ws, size_t ws_size,
                              hipStream_t stream) {
  const float* node = (const float*)d_in[0];
  const float* rel  = (const float*)d_in[1];
  const float* norm = (const float*)d_in[2];
  const float* fre  = (const float*)d_in[3];
  const float* wt   = (const float*)d_in[4];
  const float* wq   = (const float*)d_in[5];
  const float* lw   = (const float*)d_in[6];
  const float* elw  = (const float*)d_in[7];
  const int* esrc = (const int*)d_in[8];
  const int* edst = (const int*)d_in[9];
  const int* etyp = (const int*)d_in[10];
  float* out = (float*)d_out;

  char* p = (char*)d_ws;
  auto carve = [&](size_t bytes) -> char* {
    char* r = p; p += (bytes + 255) & ~(size_t)255; return r;
  };
  unsigned short* A   = (unsigned short*)carve((size_t)MP * KP * 2);
  unsigned short* Bt  = (unsigned short*)carve((size_t)NCP * KP * 2);
  unsigned short* NT2 = (unsigned short*)carve((size_t)3 * NN * 400 * 2);
  unsigned int* RelP  = (unsigned int*)carve((size_t)RRR * DD * 4);
  float* Wsq  = (float*)carve((size_t)DD * DD * 4);
  float* Wdq  = (float*)carve((size_t)DD * DD * 4);
  float* Wrq  = (float*)carve((size_t)DD * DD * 4);
  float* cq   = (float*)carve((size_t)DD * 4);
  int* deg    = (int*)carve((size_t)NN * 4);
  int* offs   = (int*)carve((size_t)(NN + 1) * 4);
  int* cursor = (int*)carve((size_t)NN * 4);
  int* spk    = (int*)carve((size_t)EE * 4);
  float* sfre = (float*)carve((size_t)EE * 4);

  const unsigned int* GSu = (const unsigned int*)NT2;
  const unsigned int* GDu = GSu + (size_t)NN * DD;
  const unsigned int* GLu = GSu + (size_t)2 * NN * DD;

  hipMemsetAsync(deg, 0, (size_t)NN * 4, stream);
  hipMemsetAsync(cursor, 0, (size_t)NN * 4, stream);

  k_wprod<<<601, 256, 0, stream>>>(wt, wq, Wsq, Wdq, Wrq, cq);
  k_node_deg<<<NN + (EE + 255) / 256, 256, 0, stream>>>(node, A, edst, deg);
  k_bt<<<NCP, 256, 0, stream>>>(wt, lw, elw, Wsq, Wdq, Bt);
  k_rel<<<RRR, 256, 0, stream>>>(rel, wt, Wrq, RelP);
  k_scan<<<1, 1024, 0, stream>>>(deg, offs);
  k_gemm<<<MT * NT, 256, 0, stream>>>(A, Bt, NT2);
  k_scatter<<<(EE + 255) / 256, 256, 0, stream>>>(esrc, edst, etyp, fre, offs, cursor,
                                                  spk, sfre);
  k_agg<<<NN, 256, 0, stream>>>(GSu, GDu, GLu, RelP, cq, norm, offs, spk, sfre, out);
}

// Round 4
// 144.089 us; speedup vs baseline: 2.0778x; 1.2400x over previous
//
#include <hip/hip_runtime.h>
#include <hip/hip_bf16.h>
#include <cstdint>
#include <cstddef>

#define DD 200
#define NN 20000
#define EE 320000
#define RRR 512
#define KP 256      // padded K stride (u16)
#define KREAL 224   // 7 * 32 covers K=200
#define MT 157      // node M tiles (157*128 = 20096)
#define NT 10       // node N tiles (1280 cols, 1200 real)
#define RMT 4       // rel M tiles (512)
#define RNT 4       // rel N tiles (512 cols, 400 real)
#define NBLK_NODE (MT * NT)

typedef __attribute__((ext_vector_type(8))) short bf16x8;
typedef __attribute__((ext_vector_type(4))) float f32x4;

__device__ __forceinline__ float bf2f_lo(unsigned int u) { return __uint_as_float(u << 16); }
__device__ __forceinline__ float bf2f_hi(unsigned int u) { return __uint_as_float(u & 0xffff0000u); }
__device__ __forceinline__ unsigned short f2bf(float f) {
  unsigned int x = __float_as_uint(f);
  return (unsigned short)((x + 0x7fffu + ((x >> 16) & 1u)) >> 16);   // RNE
}
__device__ __forceinline__ unsigned int f2bf2(float a, float b) {
  return (unsigned int)f2bf(a) | ((unsigned int)f2bf(b) << 16);
}
__device__ __forceinline__ void gl_lds16(const unsigned short* g, unsigned short* l) {
  __builtin_amdgcn_global_load_lds(
      (const __attribute__((address_space(1))) void*)g,
      (__attribute__((address_space(3))) void*)l, 16, 0, 0);
}

// ---- kA: weight prep + B-panel build + pad/counter zeroing -----------------
// blocks 0..199   : row k of Wsq/Wdq/Wrq -> write Bt/BtRel entries
// block  200      : cq = colsum(w_quad)
// blocks 201..396 : zero pad region of BtAll (k rows 200..255, all 1792 cols)
// blocks 397..553 : zero deg+cursor (2*NN ints)
__global__ __launch_bounds__(256) void kA(const float* __restrict__ wt, const float* __restrict__ wq,
                                          const float* __restrict__ lw, const float* __restrict__ elw,
                                          unsigned short* __restrict__ Bt,      // 1280 cols
                                          unsigned short* __restrict__ BtRel,   // 512 cols (contiguous after Bt)
                                          float* __restrict__ cq, int* __restrict__ degcur) {
  int b = blockIdx.x, t = threadIdx.x;
  if (b < 200) {
    int k = b, j = t;
    if (j >= DD) return;
    const float* w0 = wt + (size_t)k * DD;              // W_s row k
    const float* w1 = wt + (size_t)(2 * DD + k) * DD;   // W_d row k
    const float* w2 = wt + (size_t)(DD + k) * DD;       // W_r row k
    float s0 = 0.f, s1 = 0.f, s2 = 0.f;
    for (int i = 0; i < DD; ++i) {
      float q = wq[i * DD + j];
      s0 = fmaf(w0[i], q, s0);
      s1 = fmaf(w1[i], q, s1);
      s2 = fmaf(w2[i], q, s2);
    }
    Bt[(2 * j) * KP + k]       = f2bf(w0[j]);
    Bt[(2 * j + 1) * KP + k]   = f2bf(s0);
    Bt[(400 + 2 * j) * KP + k] = f2bf(w1[j]);
    Bt[(401 + 2 * j) * KP + k] = f2bf(s1);
    Bt[(800 + 2 * j) * KP + k] = f2bf(lw[k * DD + j]);
    Bt[(801 + 2 * j) * KP + k] = f2bf(elw[k * DD + j]);
    BtRel[(2 * j) * KP + k]     = f2bf(w2[j]);
    BtRel[(2 * j + 1) * KP + k] = f2bf(s2);
  } else if (b == 200) {
    int j = t; if (j >= DD) return;
    float s = 0.f;
    for (int i = 0; i < DD; ++i) s += wq[i * DD + j];
    cq[j] = s;
  } else if (b < 397) {
    int idx = (b - 201) * 256 + t;          // u32 index into pad (1792 cols * 28 u32)
    if (idx < 1792 * 28) {
      int col = idx / 28, kk = idx % 28;
      ((unsigned int*)Bt)[col * 128 + 100 + kk] = 0;
    }
  } else {
    int idx = (b - 397) * 256 + t;
    if (idx < 2 * NN) degcur[idx] = 0;
  }
}

// ---- k_prep: node/rel -> bf16 packed (u32), deg histogram ------------------
__global__ __launch_bounds__(128) void k_prep(const float* __restrict__ node, const float* __restrict__ rel,
                                              const int* __restrict__ dst,
                                              unsigned int* __restrict__ Au, unsigned int* __restrict__ Arelu,
                                              int* __restrict__ deg) {
  int b = blockIdx.x, t = threadIdx.x;
  if (b < NN) {
    unsigned v = 0;
    if (t < 100) { float2 f = ((const float2*)(node + (size_t)b * DD))[t]; v = f2bf2(f.x, f.y); }
    Au[(size_t)b * 128 + t] = v;
  } else if (b < NN + RRR) {
    int r = b - NN; unsigned v = 0;
    if (t < 100) { float2 f = ((const float2*)(rel + (size_t)r * DD))[t]; v = f2bf2(f.x, f.y); }
    Arelu[(size_t)r * 128 + t] = v;
  } else {
    int e = (b - NN - RRR) * 128 + t;
    if (e < EE) atomicAdd(&deg[dst[e]], 1);
  }
}

// ---- k_scan: single-block int4 exclusive scan over NN ----------------------
__global__ __launch_bounds__(1024) void k_scan(const int* __restrict__ deg, int* __restrict__ offs) {
  __shared__ int wsum[16];
  __shared__ int carry_s;
  int tid = threadIdx.x, lane = tid & 63, wv = tid >> 6;
  if (tid == 0) carry_s = 0;
  __syncthreads();
  const int4* deg4 = (const int4*)deg;
  int4* offs4 = (int4*)offs;
  for (int base = 0; base < 5000; base += 1024) {
    int idx = base + tid;
    int4 v = make_int4(0, 0, 0, 0);
    if (idx < 5000) v = deg4[idx];
    int tsum = v.x + v.y + v.z + v.w;
    int x = tsum;
#pragma unroll
    for (int off = 1; off < 64; off <<= 1) {
      int y = __shfl_up(x, off, 64);
      if (lane >= off) x += y;
    }
    if (lane == 63) wsum[wv] = x;
    __syncthreads();
    if (wv == 0) {
      int w = (lane < 16) ? wsum[lane] : 0;
#pragma unroll
      for (int off = 1; off < 16; off <<= 1) {
        int y = __shfl_up(w, off, 64);
        if (lane >= off) w += y;
      }
      if (lane < 16) wsum[lane] = w;
    }
    __syncthreads();
    int pre = carry_s + ((wv > 0) ? wsum[wv - 1] : 0) + x - tsum;
    if (idx < 5000) {
      int a = pre, b = pre + v.x, c = b + v.y, d = c + v.z;
      offs4[idx] = make_int4(a, b, c, d);
    }
    __syncthreads();
    if (tid == 1023) carry_s += wsum[15];
    __syncthreads();
  }
  if (tid == 0) offs[NN] = carry_s;
}

// ---- k_gemm: unified node (1570 blocks) + rel (16 blocks) ------------------
__global__ __launch_bounds__(256) void k_gemm(const unsigned short* __restrict__ A,
                                              const unsigned short* __restrict__ Bt,
                                              unsigned short* __restrict__ NT2u,
                                              const unsigned short* __restrict__ Arel,
                                              const unsigned short* __restrict__ BtRel,
                                              unsigned short* __restrict__ RelPu) {
  __shared__ unsigned short As[128 * 32];
  __shared__ unsigned short Bs[128 * 32];
  bool isrel = blockIdx.x >= NBLK_NODE;
  int bid, ntn;
  const unsigned short *Ag, *Bg;
  if (!isrel) { bid = blockIdx.x; ntn = NT; Ag = A; Bg = Bt; }
  else        { bid = blockIdx.x - NBLK_NODE; ntn = RNT; Ag = Arel; Bg = BtRel; }
  int mt = bid / ntn, nt = bid % ntn;
  int t = threadIdx.x, lane = t & 63, wv = t >> 6;
  int lr = lane & 15, k8 = lane >> 4;
  int wm = (wv >> 1) * 64, wn = (wv & 1) * 64;
  int sr = wv * 16 + (lane >> 2);
  int sc = lane & 3;
  f32x4 acc[4][4] = {};
  Ag += (size_t)(mt * 128) * KP;
  Bg += (size_t)(nt * 128) * KP;
  for (int kk = 0; kk < KREAL; kk += 32) {
#pragma unroll
    for (int i = 0; i < 2; ++i) {
      int row = i * 64 + sr;
      int gcol = kk + ((sc ^ (row & 3)) << 3);
      gl_lds16(Ag + (size_t)row * KP + gcol, As + i * 2048 + wv * 512);
      gl_lds16(Bg + (size_t)row * KP + gcol, Bs + i * 2048 + wv * 512);
    }
    __syncthreads();
    bf16x8 af[4], bfr[4];
#pragma unroll
    for (int mi = 0; mi < 4; ++mi) {
      int row = wm + mi * 16 + lr;
      af[mi] = *(const bf16x8*)(As + row * 32 + ((k8 ^ (row & 3)) << 3));
      int col = wn + mi * 16 + lr;
      bfr[mi] = *(const bf16x8*)(Bs + col * 32 + ((k8 ^ (col & 3)) << 3));
    }
#pragma unroll
    for (int mi = 0; mi < 4; ++mi)
#pragma unroll
      for (int ni = 0; ni < 4; ++ni)
        acc[mi][ni] = __builtin_amdgcn_mfma_f32_16x16x32_bf16(af[mi], bfr[ni], acc[mi][ni], 0, 0, 0);
    __syncthreads();
  }
  int rb = k8 * 4;
#pragma unroll
  for (int mi = 0; mi < 4; ++mi)
#pragma unroll
    for (int ni = 0; ni < 4; ++ni) {
      int col = nt * 128 + wn + ni * 16 + lr;
      if (!isrel) {
        if (col < 1200) {
          int g = col / 400, w = col - g * 400;
          unsigned short* dst = NT2u + (size_t)g * NN * 400 + w;
#pragma unroll
          for (int r = 0; r < 4; ++r) {
            int row = mt * 128 + wm + mi * 16 + rb + r;
            if (row < NN) dst[(size_t)row * 400] = f2bf(acc[mi][ni][r]);
          }
        }
      } else {
        if (col < 400) {
#pragma unroll
          for (int r = 0; r < 4; ++r) {
            int row = mt * 128 + wm + mi * 16 + rb + r;
            RelPu[(size_t)row * 400 + col] = f2bf(acc[mi][ni][r]);
          }
        }
      }
    }
}

// ---- k_scatter: edges into CSR order; pack src|typ<<15 ---------------------
__global__ __launch_bounds__(256) void k_scatter(const int* __restrict__ src, const int* __restrict__ dst,
                                                 const int* __restrict__ typ, const float* __restrict__ fre,
                                                 const int* __restrict__ offs, int* __restrict__ cursor,
                                                 int* __restrict__ spk, float* __restrict__ sfre) {
  int e = blockIdx.x * 256 + threadIdx.x;
  if (e >= EE) return;
  int d = dst[e];
  int p = offs[d] + atomicAdd(&cursor[d], 1);
  spk[p] = src[e] | (typ[e] << 15);
  sfre[p] = fre[e];
}

// ---- k_agg: per-node aggregation, 2 channels/thread, 4-edge batched --------
__global__ __launch_bounds__(128) void k_agg(const uint2* __restrict__ GS2,
                                             const uint2* __restrict__ GD2,
                                             const uint2* __restrict__ GL2,
                                             const uint2* __restrict__ Rel2,
                                             const float2* __restrict__ cq2,
                                             const float* __restrict__ norm,
                                             const int* __restrict__ offs,
                                             const int* __restrict__ spk, const float* __restrict__ sfre,
                                             float* __restrict__ out) {
  int n = blockIdx.x;
  int j2 = threadIdx.x;
  if (j2 >= 100) return;
  int e0 = offs[n], e1 = offs[n + 1];
  uint2 dp = GD2[(size_t)n * 100 + j2];
  float xd0 = bf2f_lo(dp.x), xq0 = bf2f_hi(dp.x);
  float xd1 = bf2f_lo(dp.y), xq1 = bf2f_hi(dp.y);
  float2 cqv = cq2[j2];
  float s0 = 0.f, s1 = 0.f, num0 = 0.f, num1 = 0.f;
  int i = e0;
  for (; i + 4 <= e1; i += 4) {
    int p0 = spk[i], p1 = spk[i + 1], p2 = spk[i + 2], p3 = spk[i + 3];
    float f0 = sfre[i], f1 = sfre[i + 1], f2 = sfre[i + 2], f3 = sfre[i + 3];
    uint2 sA = GS2[((unsigned)p0 & 0x7fffu) * 100u + j2];
    uint2 sB = GS2[((unsigned)p1 & 0x7fffu) * 100u + j2];
    uint2 sC = GS2[((unsigned)p2 & 0x7fffu) * 100u + j2];
    uint2 sD = GS2[((unsigned)p3 & 0x7fffu) * 100u + j2];
    uint2 rA = Rel2[((unsigned)p0 >> 15) * 100u + j2];
    uint2 rB = Rel2[((unsigned)p1 >> 15) * 100u + j2];
    uint2 rC = Rel2[((unsigned)p2 >> 15) * 100u + j2];
    uint2 rD = Rel2[((unsigned)p3 >> 15) * 100u + j2];
#define DO_EDGE(SP, RP, F)                                                    \
    {                                                                         \
      float t0 = bf2f_lo(SP.x) + bf2f_lo(RP.x) + xd0;                         \
      float a0 = bf2f_hi(SP.x) + bf2f_hi(RP.x) + fmaf(F, cqv.x, xq0);         \
      float t1 = bf2f_lo(SP.y) + bf2f_lo(RP.y) + xd1;                         \
      float a1 = bf2f_hi(SP.y) + bf2f_hi(RP.y) + fmaf(F, cqv.y, xq1);         \
      a0 = fmaxf(a0, 0.01f * a0); a1 = fmaxf(a1, 0.01f * a1);                 \
      float ev0 = __expf(a0), ev1 = __expf(a1);                               \
      s0 += ev0; num0 = fmaf(ev0, t0, num0);                                  \
      s1 += ev1; num1 = fmaf(ev1, t1, num1);                                  \
    }
    DO_EDGE(sA, rA, f0)
    DO_EDGE(sB, rB, f1)
    DO_EDGE(sC, rC, f2)
    DO_EDGE(sD, rD, f3)
  }
  for (; i < e1; ++i) {
    int p = spk[i]; float f = sfre[i];
    uint2 sp = GS2[((unsigned)p & 0x7fffu) * 100u + j2];
    uint2 rp = Rel2[((unsigned)p >> 15) * 100u + j2];
    DO_EDGE(sp, rp, f)
  }
#undef DO_EDGE
  uint2 lp = GL2[(size_t)n * 100 + j2];
  float o0, o1;
  if (e1 > e0) {
    float nm = norm[n];
    o0 = (num0 / s0) * nm + bf2f_lo(lp.x);
    o1 = (num1 / s1) * nm + bf2f_lo(lp.y);
  } else {
    o0 = bf2f_hi(lp.x);
    o1 = bf2f_hi(lp.y);
  }
  ((float2*)(out + (size_t)n * DD))[j2] = make_float2(fmaxf(o0, 0.f), fmaxf(o1, 0.f));
}

extern "C" void kernel_launch(void* const* d_in, const int* in_sizes, int n_in,
                              void* d_out, int out_size, void* d_ws, size_t ws_size,
                              hipStream_t stream) {
  const float* node = (const float*)d_in[0];
  const float* rel  = (const float*)d_in[1];
  const float* norm = (const float*)d_in[2];
  const float* fre  = (const float*)d_in[3];
  const float* wt   = (const float*)d_in[4];
  const float* wq   = (const float*)d_in[5];
  const float* lw   = (const float*)d_in[6];
  const float* elw  = (const float*)d_in[7];
  const int* esrc = (const int*)d_in[8];
  const int* edst = (const int*)d_in[9];
  const int* etyp = (const int*)d_in[10];
  float* out = (float*)d_out;

  char* p = (char*)d_ws;
  auto carve = [&](size_t bytes) -> char* {
    char* r = p; p += (bytes + 255) & ~(size_t)255; return r;
  };
  unsigned short* A     = (unsigned short*)carve((size_t)(MT * 128) * KP * 2);
  unsigned short* Arel  = (unsigned short*)carve((size_t)RRR * KP * 2);
  unsigned short* BtAll = (unsigned short*)carve((size_t)(1280 + 512) * KP * 2);  // Bt | BtRel contiguous
  unsigned short* NT2   = (unsigned short*)carve((size_t)3 * NN * 400 * 2);
  unsigned short* RelP  = (unsigned short*)carve((size_t)RRR * 400 * 2);
  float* cq   = (float*)carve((size_t)DD * 4);
  int* degcur = (int*)carve((size_t)2 * NN * 4);     // deg | cursor
  int* offs   = (int*)carve((size_t)(NN + 1) * 4);
  int* spk    = (int*)carve((size_t)EE * 4);
  float* sfre = (float*)carve((size_t)EE * 4);

  unsigned short* Bt    = BtAll;
  unsigned short* BtRel = BtAll + (size_t)1280 * KP;
  int* deg    = degcur;
  int* cursor = degcur + NN;

  const uint2* GS2 = (const uint2*)NT2;
  const uint2* GD2 = GS2 + (size_t)NN * 100;
  const uint2* GL2 = GS2 + (size_t)2 * NN * 100;

  kA<<<554, 256, 0, stream>>>(wt, wq, lw, elw, Bt, BtRel, cq, degcur);
  k_prep<<<NN + RRR + (EE + 127) / 128, 128, 0, stream>>>(node, rel, edst,
                                                          (unsigned int*)A, (unsigned int*)Arel, deg);
  k_scan<<<1, 1024, 0, stream>>>(deg, offs);
  k_gemm<<<NBLK_NODE + RMT * RNT, 256, 0, stream>>>(A, Bt, NT2, Arel, BtRel, RelP);
  k_scatter<<<(EE + 255) / 256, 256, 0, stream>>>(esrc, edst, etyp, fre, offs, cursor,
                                                  spk, sfre);
  k_agg<<<NN, 128, 0, stream>>>(GS2, GD2, GL2, (const uint2*)RelP, (const float2*)cq,
                                norm, offs, spk, sfre, out);
}

// Round 5
// 142.252 us; speedup vs baseline: 2.1046x; 1.0129x over previous
//
#include <hip/hip_runtime.h>
#include <hip/hip_bf16.h>
#include <cstdint>
#include <cstddef>

#define DD 200
#define NN 20000
#define EE 320000
#define RRR 512
#define KP 256      // padded K stride (u16)
#define KREAL 224   // 7 * 32 covers K=200
#define MT 157      // node M tiles (157*128 = 20096)
#define NT 10       // node N tiles (1280 cols, 1200 real)
#define RMT 4
#define RNT 4
#define NBLK_NODE (MT * NT)

// kPrep block ranges
#define PB_NODE 10000
#define PB_REL  (PB_NODE + 256)
#define PB_HIST (PB_REL + 1250)
#define PB_W    (PB_HIST + 200)
#define PB_CQ   (PB_W + 1)
#define PB_PAD  (PB_CQ + 196)     // 1792 cols * 28 u32 = 50176 = 196*256

typedef __attribute__((ext_vector_type(8))) short bf16x8;
typedef __attribute__((ext_vector_type(4))) float f32x4;

__device__ __forceinline__ float bf2f_lo(unsigned int u) { return __uint_as_float(u << 16); }
__device__ __forceinline__ float bf2f_hi(unsigned int u) { return __uint_as_float(u & 0xffff0000u); }
__device__ __forceinline__ unsigned short f2bf(float f) {
  unsigned int x = __float_as_uint(f);
  return (unsigned short)((x + 0x7fffu + ((x >> 16) & 1u)) >> 16);   // RNE
}
__device__ __forceinline__ unsigned int f2bf2(float a, float b) {
  return (unsigned int)f2bf(a) | ((unsigned int)f2bf(b) << 16);
}
__device__ __forceinline__ void gl_lds16(const unsigned short* g, unsigned short* l) {
  __builtin_amdgcn_global_load_lds(
      (const __attribute__((address_space(1))) void*)g,
      (__attribute__((address_space(3))) void*)l, 16, 0, 0);
}

// ---- kPrep: all independent prep in one launch ------------------------------
__global__ __launch_bounds__(256) void kPrep(const float* __restrict__ node, const float* __restrict__ rel,
                                             const int* __restrict__ dst,
                                             const float* __restrict__ wt, const float* __restrict__ wq,
                                             const float* __restrict__ lw, const float* __restrict__ elw,
                                             unsigned int* __restrict__ Au, unsigned int* __restrict__ Arelu,
                                             int* __restrict__ deg,
                                             unsigned short* __restrict__ Bt, unsigned short* __restrict__ BtRel,
                                             float* __restrict__ cq) {
  int b = blockIdx.x, t = threadIdx.x;
  if (b < PB_NODE) {                       // node -> packed bf16 (2 nodes/block)
    int h = t >> 7, tt = t & 127;
    int n = b * 2 + h;
    unsigned v = 0;
    if (tt < 100) { float2 f = ((const float2*)(node + (size_t)n * DD))[tt]; v = f2bf2(f.x, f.y); }
    Au[(size_t)n * 128 + tt] = v;
  } else if (b < PB_REL) {                 // rel -> packed bf16 (2 rels/block)
    int h = t >> 7, tt = t & 127;
    int r = (b - PB_NODE) * 2 + h;
    unsigned v = 0;
    if (tt < 100) { float2 f = ((const float2*)(rel + (size_t)r * DD))[tt]; v = f2bf2(f.x, f.y); }
    Arelu[(size_t)r * 128 + tt] = v;
  } else if (b < PB_HIST) {                // degree histogram
    int e = (b - PB_REL) * 256 + t;
    if (e < EE) atomicAdd(&deg[dst[e]], 1);
  } else if (b < PB_W) {                   // weight row k -> B panels
    int k = b - PB_HIST, j = t;
    if (j >= DD) return;
    const float* w0 = wt + (size_t)k * DD;              // W_s row k
    const float* w1 = wt + (size_t)(2 * DD + k) * DD;   // W_d row k
    const float* w2 = wt + (size_t)(DD + k) * DD;       // W_r row k
    float s0 = 0.f, s1 = 0.f, s2 = 0.f;
    for (int i = 0; i < DD; ++i) {
      float q = wq[i * DD + j];
      s0 = fmaf(w0[i], q, s0);
      s1 = fmaf(w1[i], q, s1);
      s2 = fmaf(w2[i], q, s2);
    }
    Bt[(2 * j) * KP + k]       = f2bf(w0[j]);
    Bt[(2 * j + 1) * KP + k]   = f2bf(s0);
    Bt[(400 + 2 * j) * KP + k] = f2bf(w1[j]);
    Bt[(401 + 2 * j) * KP + k] = f2bf(s1);
    Bt[(800 + 2 * j) * KP + k] = f2bf(lw[k * DD + j]);
    Bt[(801 + 2 * j) * KP + k] = f2bf(elw[k * DD + j]);
    BtRel[(2 * j) * KP + k]     = f2bf(w2[j]);
    BtRel[(2 * j + 1) * KP + k] = f2bf(s2);
  } else if (b < PB_CQ) {                  // cq = colsum(w_quad)
    int j = t; if (j >= DD) return;
    float s = 0.f;
    for (int i = 0; i < DD; ++i) s += wq[i * DD + j];
    cq[j] = s;
  } else {                                 // zero K-pad of BtAll (cols 0..1791, k 200..255)
    int idx = (b - PB_CQ) * 256 + t;       // < 50176
    ((unsigned int*)Bt)[(idx / 28) * 128 + 100 + idx % 28] = 0;
  }
}

// ---- k_scan: single-block, single-pass exclusive scan (thread owns 5 int4) --
__global__ __launch_bounds__(1024) void k_scan(const int* __restrict__ deg, int* __restrict__ offs) {
  __shared__ int wsum[16];
  int tid = threadIdx.x, lane = tid & 63, wv = tid >> 6;
  const int4* deg4 = (const int4*)deg;
  int4* offs4 = (int4*)offs;
  int4 v[5]; int ps[5]; int tsum = 0;
#pragma unroll
  for (int c = 0; c < 5; ++c) {
    int idx = tid * 5 + c;
    v[c] = (idx < 5000) ? deg4[idx] : make_int4(0, 0, 0, 0);
    ps[c] = tsum;
    tsum += v[c].x + v[c].y + v[c].z + v[c].w;
  }
  int x = tsum;
#pragma unroll
  for (int off = 1; off < 64; off <<= 1) {
    int y = __shfl_up(x, off, 64);
    if (lane >= off) x += y;
  }
  if (lane == 63) wsum[wv] = x;
  __syncthreads();
  if (wv == 0) {
    int w = (lane < 16) ? wsum[lane] : 0;
#pragma unroll
    for (int off = 1; off < 16; off <<= 1) {
      int y = __shfl_up(w, off, 64);
      if (lane >= off) w += y;
    }
    if (lane < 16) wsum[lane] = w;
  }
  __syncthreads();
  int pre = ((wv > 0) ? wsum[wv - 1] : 0) + x - tsum;
#pragma unroll
  for (int c = 0; c < 5; ++c) {
    int idx = tid * 5 + c;
    if (idx < 5000) {
      int a = pre + ps[c];
      int bq = a + v[c].x, cc = bq + v[c].y, d = cc + v[c].z;
      offs4[idx] = make_int4(a, bq, cc, d);
    }
  }
  if (tid == 0) offs[NN] = wsum[15];
}

// ---- k_gemm: unified node (1570 blocks) + rel (16 blocks) -------------------
__global__ __launch_bounds__(256) void k_gemm(const unsigned short* __restrict__ A,
                                              const unsigned short* __restrict__ Bt,
                                              unsigned short* __restrict__ NT2u,
                                              const unsigned short* __restrict__ Arel,
                                              const unsigned short* __restrict__ BtRel,
                                              unsigned short* __restrict__ RelPu) {
  __shared__ unsigned short As[128 * 32];
  __shared__ unsigned short Bs[128 * 32];
  bool isrel = blockIdx.x >= NBLK_NODE;
  int bid, ntn;
  const unsigned short *Ag, *Bg;
  if (!isrel) { bid = blockIdx.x; ntn = NT; Ag = A; Bg = Bt; }
  else        { bid = blockIdx.x - NBLK_NODE; ntn = RNT; Ag = Arel; Bg = BtRel; }
  int mt = bid / ntn, nt = bid % ntn;
  int t = threadIdx.x, lane = t & 63, wv = t >> 6;
  int lr = lane & 15, k8 = lane >> 4;
  int wm = (wv >> 1) * 64, wn = (wv & 1) * 64;
  int sr = wv * 16 + (lane >> 2);
  int sc = lane & 3;
  f32x4 acc[4][4] = {};
  Ag += (size_t)(mt * 128) * KP;
  Bg += (size_t)(nt * 128) * KP;
  for (int kk = 0; kk < KREAL; kk += 32) {
#pragma unroll
    for (int i = 0; i < 2; ++i) {
      int row = i * 64 + sr;
      int gcol = kk + ((sc ^ (row & 3)) << 3);
      gl_lds16(Ag + (size_t)row * KP + gcol, As + i * 2048 + wv * 512);
      gl_lds16(Bg + (size_t)row * KP + gcol, Bs + i * 2048 + wv * 512);
    }
    __syncthreads();
    bf16x8 af[4], bfr[4];
#pragma unroll
    for (int mi = 0; mi < 4; ++mi) {
      int row = wm + mi * 16 + lr;
      af[mi] = *(const bf16x8*)(As + row * 32 + ((k8 ^ (row & 3)) << 3));
      int col = wn + mi * 16 + lr;
      bfr[mi] = *(const bf16x8*)(Bs + col * 32 + ((k8 ^ (col & 3)) << 3));
    }
#pragma unroll
    for (int mi = 0; mi < 4; ++mi)
#pragma unroll
      for (int ni = 0; ni < 4; ++ni)
        acc[mi][ni] = __builtin_amdgcn_mfma_f32_16x16x32_bf16(af[mi], bfr[ni], acc[mi][ni], 0, 0, 0);
    __syncthreads();
  }
  int rb = k8 * 4;
#pragma unroll
  for (int mi = 0; mi < 4; ++mi)
#pragma unroll
    for (int ni = 0; ni < 4; ++ni) {
      int col = nt * 128 + wn + ni * 16 + lr;
      if (!isrel) {
        if (col < 1200) {
          int g = col / 400, w = col - g * 400;
          unsigned short* dst = NT2u + (size_t)g * NN * 400 + w;
#pragma unroll
          for (int r = 0; r < 4; ++r) {
            int row = mt * 128 + wm + mi * 16 + rb + r;
            if (row < NN) dst[(size_t)row * 400] = f2bf(acc[mi][ni][r]);
          }
        }
      } else {
        if (col < 400) {
#pragma unroll
          for (int r = 0; r < 4; ++r) {
            int row = mt * 128 + wm + mi * 16 + rb + r;
            RelPu[(size_t)row * 400 + col] = f2bf(acc[mi][ni][r]);
          }
        }
      }
    }
}

// ---- k_scatter: edges into CSR order; one int2 record/edge ------------------
__global__ __launch_bounds__(256) void k_scatter(const int* __restrict__ src, const int* __restrict__ dst,
                                                 const int* __restrict__ typ, const float* __restrict__ fre,
                                                 const int* __restrict__ offs, int* __restrict__ cursor,
                                                 int2* __restrict__ erec) {
  int e = blockIdx.x * 256 + threadIdx.x;
  if (e >= EE) return;
  int d = dst[e];
  int p = offs[d] + atomicAdd(&cursor[d], 1);
  erec[p] = make_int2(src[e] | (typ[e] << 15), __float_as_int(fre[e]));
}

// ---- k_agg: per-node aggregation, 8-edge batched gathers --------------------
__global__ __launch_bounds__(128) void k_agg(const uint2* __restrict__ GS2,
                                             const uint2* __restrict__ GD2,
                                             const uint2* __restrict__ GL2,
                                             const uint2* __restrict__ Rel2,
                                             const float2* __restrict__ cq2,
                                             const float* __restrict__ norm,
                                             const int* __restrict__ offs,
                                             const int2* __restrict__ erec,
                                             float* __restrict__ out) {
  int n = blockIdx.x;
  int j2 = threadIdx.x;
  if (j2 >= 100) return;
  int e0 = offs[n], e1 = offs[n + 1];
  uint2 dp = GD2[(size_t)n * 100 + j2];
  float xd0 = bf2f_lo(dp.x), xq0 = bf2f_hi(dp.x);
  float xd1 = bf2f_lo(dp.y), xq1 = bf2f_hi(dp.y);
  float2 cqv = cq2[j2];
  float s0 = 0.f, s1 = 0.f, num0 = 0.f, num1 = 0.f;
#define DO_EDGE(SP, RP, FI)                                                   \
  {                                                                           \
    float F = __int_as_float(FI);                                             \
    float t0 = bf2f_lo(SP.x) + bf2f_lo(RP.x);                                 \
    float a0 = bf2f_hi(SP.x) + bf2f_hi(RP.x) + fmaf(F, cqv.x, xq0);           \
    float t1 = bf2f_lo(SP.y) + bf2f_lo(RP.y);                                 \
    float a1 = bf2f_hi(SP.y) + bf2f_hi(RP.y) + fmaf(F, cqv.y, xq1);           \
    a0 = fmaxf(a0, 0.01f * a0); a1 = fmaxf(a1, 0.01f * a1);                   \
    float ev0 = __expf(a0), ev1 = __expf(a1);                                 \
    s0 += ev0; num0 = fmaf(ev0, t0, num0);                                    \
    s1 += ev1; num1 = fmaf(ev1, t1, num1);                                    \
  }
  int i = e0;
  for (; i + 8 <= e1; i += 8) {
    int2 r[8]; uint2 g[8], R[8];
#pragma unroll
    for (int u = 0; u < 8; ++u) r[u] = erec[i + u];
#pragma unroll
    for (int u = 0; u < 8; ++u) g[u] = GS2[((unsigned)r[u].x & 0x7fffu) * 100u + j2];
#pragma unroll
    for (int u = 0; u < 8; ++u) R[u] = Rel2[((unsigned)r[u].x >> 15) * 100u + j2];
#pragma unroll
    for (int u = 0; u < 8; ++u) DO_EDGE(g[u], R[u], r[u].y)
  }
  if (i + 4 <= e1) {
    int2 r[4]; uint2 g[4], R[4];
#pragma unroll
    for (int u = 0; u < 4; ++u) r[u] = erec[i + u];
#pragma unroll
    for (int u = 0; u < 4; ++u) g[u] = GS2[((unsigned)r[u].x & 0x7fffu) * 100u + j2];
#pragma unroll
    for (int u = 0; u < 4; ++u) R[u] = Rel2[((unsigned)r[u].x >> 15) * 100u + j2];
#pragma unroll
    for (int u = 0; u < 4; ++u) DO_EDGE(g[u], R[u], r[u].y)
    i += 4;
  }
  for (; i < e1; ++i) {
    int2 r = erec[i];
    uint2 g = GS2[((unsigned)r.x & 0x7fffu) * 100u + j2];
    uint2 R = Rel2[((unsigned)r.x >> 15) * 100u + j2];
    DO_EDGE(g, R, r.y)
  }
#undef DO_EDGE
  uint2 lp = GL2[(size_t)n * 100 + j2];
  float o0, o1;
  if (e1 > e0) {
    float nm = norm[n];
    o0 = (num0 / s0 + xd0) * nm + bf2f_lo(lp.x);
    o1 = (num1 / s1 + xd1) * nm + bf2f_lo(lp.y);
  } else {
    o0 = bf2f_hi(lp.x);
    o1 = bf2f_hi(lp.y);
  }
  ((float2*)(out + (size_t)n * DD))[j2] = make_float2(fmaxf(o0, 0.f), fmaxf(o1, 0.f));
}

extern "C" void kernel_launch(void* const* d_in, const int* in_sizes, int n_in,
                              void* d_out, int out_size, void* d_ws, size_t ws_size,
                              hipStream_t stream) {
  const float* node = (const float*)d_in[0];
  const float* rel  = (const float*)d_in[1];
  const float* norm = (const float*)d_in[2];
  const float* fre  = (const float*)d_in[3];
  const float* wt   = (const float*)d_in[4];
  const float* wq   = (const float*)d_in[5];
  const float* lw   = (const float*)d_in[6];
  const float* elw  = (const float*)d_in[7];
  const int* esrc = (const int*)d_in[8];
  const int* edst = (const int*)d_in[9];
  const int* etyp = (const int*)d_in[10];
  float* out = (float*)d_out;

  char* p = (char*)d_ws;
  auto carve = [&](size_t bytes) -> char* {
    char* r = p; p += (bytes + 255) & ~(size_t)255; return r;
  };
  unsigned short* A     = (unsigned short*)carve((size_t)(MT * 128) * KP * 2);
  unsigned short* Arel  = (unsigned short*)carve((size_t)RRR * KP * 2);
  unsigned short* BtAll = (unsigned short*)carve((size_t)(1280 + 512) * KP * 2);
  unsigned short* NT2   = (unsigned short*)carve((size_t)3 * NN * 400 * 2);
  unsigned short* RelP  = (unsigned short*)carve((size_t)RRR * 400 * 2);
  float* cq   = (float*)carve((size_t)DD * 4);
  int* degcur = (int*)carve((size_t)2 * NN * 4);     // deg | cursor
  int* offs   = (int*)carve((size_t)(NN + 1) * 4);
  int2* erec  = (int2*)carve((size_t)EE * 8);

  unsigned short* Bt    = BtAll;
  unsigned short* BtRel = BtAll + (size_t)1280 * KP;
  int* deg    = degcur;
  int* cursor = degcur + NN;

  const uint2* GS2 = (const uint2*)NT2;
  const uint2* GD2 = GS2 + (size_t)NN * 100;
  const uint2* GL2 = GS2 + (size_t)2 * NN * 100;

  hipMemsetAsync(degcur, 0, (size_t)2 * NN * 4, stream);
  kPrep<<<PB_PAD, 256, 0, stream>>>(node, rel, edst, wt, wq, lw, elw,
                                    (unsigned int*)A, (unsigned int*)Arel, deg, Bt, BtRel, cq);
  k_scan<<<1, 1024, 0, stream>>>(deg, offs);
  k_scatter<<<(EE + 255) / 256, 256, 0, stream>>>(esrc, edst, etyp, fre, offs, cursor, erec);
  k_gemm<<<NBLK_NODE + RMT * RNT, 256, 0, stream>>>(A, Bt, NT2, Arel, BtRel, RelP);
  k_agg<<<NN, 128, 0, stream>>>(GS2, GD2, GL2, (const uint2*)RelP, (const float2*)cq,
                                norm, offs, erec, out);
}

// Round 6
// 134.171 us; speedup vs baseline: 2.2314x; 1.0602x over previous
//
#include <hip/hip_runtime.h>
#include <hip/hip_bf16.h>
#include <cstdint>
#include <cstddef>

#define DD 200
#define NN 20000
#define EE 320000
#define RRR 512
#define KP 256      // padded K stride (u16)
#define KREAL 224   // 7 * 32 covers K=200
#define MT 157      // node M tiles (157*128 = 20096)
#define NT 10       // node N tiles (1280 cols, 1200 real)
#define RMT 4
#define RNT 4
#define NBLK_NODE (MT * NT)
#define NBLK_GEMM (NBLK_NODE + RMT * RNT)
#define NBLK_SCAT ((EE + 255) / 256)
#define LOG2E 1.4426950408889634f

// kPrep block ranges
#define PB_NODE 10000
#define PB_REL  (PB_NODE + 256)
#define PB_HIST (PB_REL + 1250)
#define PB_W    (PB_HIST + 200)
#define PB_CQ   (PB_W + 1)
#define PB_PAD  (PB_CQ + 196)     // 1792 cols * 28 u32 = 50176 = 196*256

typedef __attribute__((ext_vector_type(8))) short bf16x8;
typedef __attribute__((ext_vector_type(4))) float f32x4;

__device__ __forceinline__ float bf2f_lo(unsigned int u) { return __uint_as_float(u << 16); }
__device__ __forceinline__ float bf2f_hi(unsigned int u) { return __uint_as_float(u & 0xffff0000u); }
__device__ __forceinline__ unsigned short f2bf(float f) {
  unsigned int x = __float_as_uint(f);
  return (unsigned short)((x + 0x7fffu + ((x >> 16) & 1u)) >> 16);   // RNE
}
__device__ __forceinline__ unsigned int f2bf2(float a, float b) {
  return (unsigned int)f2bf(a) | ((unsigned int)f2bf(b) << 16);
}
__device__ __forceinline__ void gl_lds16(const unsigned short* g, unsigned short* l) {
  __builtin_amdgcn_global_load_lds(
      (const __attribute__((address_space(1))) void*)g,
      (__attribute__((address_space(3))) void*)l, 16, 0, 0);
}

// ---- kPrep: all independent prep in one launch ------------------------------
// q-path weights (Wsq, Wdq, Wrq, cq) are pre-scaled by LOG2E so k_agg can use
// native exp2 with no per-edge multiply (exact through leaky-relu: scale > 0).
__global__ __launch_bounds__(256) void kPrep(const float* __restrict__ node, const float* __restrict__ rel,
                                             const int* __restrict__ dst,
                                             const float* __restrict__ wt, const float* __restrict__ wq,
                                             const float* __restrict__ lw, const float* __restrict__ elw,
                                             unsigned int* __restrict__ Au, unsigned int* __restrict__ Arelu,
                                             int* __restrict__ deg,
                                             unsigned short* __restrict__ Bt, unsigned short* __restrict__ BtRel,
                                             float* __restrict__ cq) {
  int b = blockIdx.x, t = threadIdx.x;
  if (b < PB_NODE) {                       // node -> packed bf16 (2 nodes/block)
    int h = t >> 7, tt = t & 127;
    int n = b * 2 + h;
    unsigned v = 0;
    if (tt < 100) { float2 f = ((const float2*)(node + (size_t)n * DD))[tt]; v = f2bf2(f.x, f.y); }
    Au[(size_t)n * 128 + tt] = v;
  } else if (b < PB_REL) {                 // rel -> packed bf16 (2 rels/block)
    int h = t >> 7, tt = t & 127;
    int r = (b - PB_NODE) * 2 + h;
    unsigned v = 0;
    if (tt < 100) { float2 f = ((const float2*)(rel + (size_t)r * DD))[tt]; v = f2bf2(f.x, f.y); }
    Arelu[(size_t)r * 128 + tt] = v;
  } else if (b < PB_HIST) {                // degree histogram
    int e = (b - PB_REL) * 256 + t;
    if (e < EE) atomicAdd(&deg[dst[e]], 1);
  } else if (b < PB_W) {                   // weight row k -> B panels
    int k = b - PB_HIST, j = t;
    if (j >= DD) return;
    const float* w0 = wt + (size_t)k * DD;              // W_s row k
    const float* w1 = wt + (size_t)(2 * DD + k) * DD;   // W_d row k
    const float* w2 = wt + (size_t)(DD + k) * DD;       // W_r row k
    float s0 = 0.f, s1 = 0.f, s2 = 0.f;
    for (int i = 0; i < DD; ++i) {
      float q = wq[i * DD + j];
      s0 = fmaf(w0[i], q, s0);
      s1 = fmaf(w1[i], q, s1);
      s2 = fmaf(w2[i], q, s2);
    }
    Bt[(2 * j) * KP + k]       = f2bf(w0[j]);
    Bt[(2 * j + 1) * KP + k]   = f2bf(s0 * LOG2E);
    Bt[(400 + 2 * j) * KP + k] = f2bf(w1[j]);
    Bt[(401 + 2 * j) * KP + k] = f2bf(s1 * LOG2E);
    Bt[(800 + 2 * j) * KP + k] = f2bf(lw[k * DD + j]);
    Bt[(801 + 2 * j) * KP + k] = f2bf(elw[k * DD + j]);
    BtRel[(2 * j) * KP + k]     = f2bf(w2[j]);
    BtRel[(2 * j + 1) * KP + k] = f2bf(s2 * LOG2E);
  } else if (b < PB_CQ) {                  // cq = colsum(w_quad) * LOG2E
    int j = t; if (j >= DD) return;
    float s = 0.f;
    for (int i = 0; i < DD; ++i) s += wq[i * DD + j];
    cq[j] = s * LOG2E;
  } else {                                 // zero K-pad of BtAll (cols 0..1791, k 200..255)
    int idx = (b - PB_CQ) * 256 + t;       // < 50176
    ((unsigned int*)Bt)[(idx / 28) * 128 + 100 + idx % 28] = 0;
  }
}

// ---- k_scan: single-block, single-pass exclusive scan (thread owns 5 int4) --
__global__ __launch_bounds__(1024) void k_scan(const int* __restrict__ deg, int* __restrict__ offs) {
  __shared__ int wsum[16];
  int tid = threadIdx.x, lane = tid & 63, wv = tid >> 6;
  const int4* deg4 = (const int4*)deg;
  int4* offs4 = (int4*)offs;
  int4 v[5]; int ps[5]; int tsum = 0;
#pragma unroll
  for (int c = 0; c < 5; ++c) {
    int idx = tid * 5 + c;
    v[c] = (idx < 5000) ? deg4[idx] : make_int4(0, 0, 0, 0);
    ps[c] = tsum;
    tsum += v[c].x + v[c].y + v[c].z + v[c].w;
  }
  int x = tsum;
#pragma unroll
  for (int off = 1; off < 64; off <<= 1) {
    int y = __shfl_up(x, off, 64);
    if (lane >= off) x += y;
  }
  if (lane == 63) wsum[wv] = x;
  __syncthreads();
  if (wv == 0) {
    int w = (lane < 16) ? wsum[lane] : 0;
#pragma unroll
    for (int off = 1; off < 16; off <<= 1) {
      int y = __shfl_up(w, off, 64);
      if (lane >= off) w += y;
    }
    if (lane < 16) wsum[lane] = w;
  }
  __syncthreads();
  int pre = ((wv > 0) ? wsum[wv - 1] : 0) + x - tsum;
#pragma unroll
  for (int c = 0; c < 5; ++c) {
    int idx = tid * 5 + c;
    if (idx < 5000) {
      int a = pre + ps[c];
      int bq = a + v[c].x, cc = bq + v[c].y, d = cc + v[c].z;
      offs4[idx] = make_int4(a, bq, cc, d);
    }
  }
  if (tid == 0) offs[NN] = wsum[15];
}

// ---- k_gs: fused GEMM (node 1570 + rel 16 blocks) + edge scatter (1250) -----
__global__ __launch_bounds__(256) void k_gs(const unsigned short* __restrict__ A,
                                            const unsigned short* __restrict__ Bt,
                                            unsigned short* __restrict__ NT2u,
                                            const unsigned short* __restrict__ Arel,
                                            const unsigned short* __restrict__ BtRel,
                                            unsigned short* __restrict__ RelPu,
                                            const int* __restrict__ esrc, const int* __restrict__ edst,
                                            const int* __restrict__ etyp, const float* __restrict__ fre,
                                            const int* __restrict__ offs, int* __restrict__ cursor,
                                            int2* __restrict__ erec) {
  __shared__ unsigned short As[128 * 32];
  __shared__ unsigned short Bs[128 * 32];
  if (blockIdx.x >= NBLK_GEMM) {           // ---- scatter path ----
    int e = (blockIdx.x - NBLK_GEMM) * 256 + threadIdx.x;
    if (e >= EE) return;
    int d = edst[e];
    int p = offs[d] + atomicAdd(&cursor[d], 1);
    erec[p] = make_int2(esrc[e] | (etyp[e] << 15), __float_as_int(fre[e]));
    return;
  }
  // ---- GEMM path ----
  bool isrel = blockIdx.x >= NBLK_NODE;
  int bid, ntn;
  const unsigned short *Ag, *Bg;
  if (!isrel) { bid = blockIdx.x; ntn = NT; Ag = A; Bg = Bt; }
  else        { bid = blockIdx.x - NBLK_NODE; ntn = RNT; Ag = Arel; Bg = BtRel; }
  int mt = bid / ntn, nt = bid % ntn;
  int t = threadIdx.x, lane = t & 63, wv = t >> 6;
  int lr = lane & 15, k8 = lane >> 4;
  int wm = (wv >> 1) * 64, wn = (wv & 1) * 64;
  int sr = wv * 16 + (lane >> 2);
  int sc = lane & 3;
  f32x4 acc[4][4] = {};
  Ag += (size_t)(mt * 128) * KP;
  Bg += (size_t)(nt * 128) * KP;
  for (int kk = 0; kk < KREAL; kk += 32) {
#pragma unroll
    for (int i = 0; i < 2; ++i) {
      int row = i * 64 + sr;
      int gcol = kk + ((sc ^ (row & 3)) << 3);
      gl_lds16(Ag + (size_t)row * KP + gcol, As + i * 2048 + wv * 512);
      gl_lds16(Bg + (size_t)row * KP + gcol, Bs + i * 2048 + wv * 512);
    }
    __syncthreads();
    bf16x8 af[4], bfr[4];
#pragma unroll
    for (int mi = 0; mi < 4; ++mi) {
      int row = wm + mi * 16 + lr;
      af[mi] = *(const bf16x8*)(As + row * 32 + ((k8 ^ (row & 3)) << 3));
      int col = wn + mi * 16 + lr;
      bfr[mi] = *(const bf16x8*)(Bs + col * 32 + ((k8 ^ (col & 3)) << 3));
    }
#pragma unroll
    for (int mi = 0; mi < 4; ++mi)
#pragma unroll
      for (int ni = 0; ni < 4; ++ni)
        acc[mi][ni] = __builtin_amdgcn_mfma_f32_16x16x32_bf16(af[mi], bfr[ni], acc[mi][ni], 0, 0, 0);
    __syncthreads();
  }
  int rb = k8 * 4;
#pragma unroll
  for (int mi = 0; mi < 4; ++mi)
#pragma unroll
    for (int ni = 0; ni < 4; ++ni) {
      int col = nt * 128 + wn + ni * 16 + lr;
      if (!isrel) {
        if (col < 1200) {
          int g = col / 400, w = col - g * 400;
          unsigned short* dst = NT2u + (size_t)g * NN * 400 + w;
#pragma unroll
          for (int r = 0; r < 4; ++r) {
            int row = mt * 128 + wm + mi * 16 + rb + r;
            if (row < NN) dst[(size_t)row * 400] = f2bf(acc[mi][ni][r]);
          }
        }
      } else {
        if (col < 400) {
#pragma unroll
          for (int r = 0; r < 4; ++r) {
            int row = mt * 128 + wm + mi * 16 + rb + r;
            RelPu[(size_t)row * 400 + col] = f2bf(acc[mi][ni][r]);
          }
        }
      }
    }
}

// ---- k_agg: per-node aggregation, 2-deep pipelined batch-4 gathers ----------
__global__ __launch_bounds__(128) void k_agg(const uint2* __restrict__ GS2,
                                             const uint2* __restrict__ GD2,
                                             const uint2* __restrict__ GL2,
                                             const uint2* __restrict__ Rel2,
                                             const float2* __restrict__ cq2,
                                             const float* __restrict__ norm,
                                             const int* __restrict__ offs,
                                             const int2* __restrict__ erec,
                                             float* __restrict__ out) {
  int n = blockIdx.x;
  int j2 = threadIdx.x;
  if (j2 >= 100) return;
  int e0 = offs[n], e1 = offs[n + 1];
  uint2 dp = GD2[(size_t)n * 100 + j2];
  float xd0 = bf2f_lo(dp.x), xq0 = bf2f_hi(dp.x);
  float xd1 = bf2f_lo(dp.y), xq1 = bf2f_hi(dp.y);
  float2 cqv = cq2[j2];
  float s0 = 0.f, s1 = 0.f, num0 = 0.f, num1 = 0.f;
#define DO_EDGE(SP, RP, FI)                                                   \
  {                                                                           \
    float F = __int_as_float(FI);                                             \
    float t0 = bf2f_lo(SP.x) + bf2f_lo(RP.x);                                 \
    float a0 = bf2f_hi(SP.x) + bf2f_hi(RP.x) + fmaf(F, cqv.x, xq0);           \
    float t1 = bf2f_lo(SP.y) + bf2f_lo(RP.y);                                 \
    float a1 = bf2f_hi(SP.y) + bf2f_hi(RP.y) + fmaf(F, cqv.y, xq1);           \
    a0 = fmaxf(a0, 0.01f * a0); a1 = fmaxf(a1, 0.01f * a1);                   \
    float ev0 = exp2f(a0), ev1 = exp2f(a1);                                   \
    s0 += ev0; num0 = fmaf(ev0, t0, num0);                                    \
    s1 += ev1; num1 = fmaf(ev1, t1, num1);                                    \
  }
#define LOADB(R, GS, GR, base)                                                \
  {                                                                           \
    _Pragma("unroll")                                                         \
    for (int u = 0; u < 4; ++u) R[u] = erec[(base) + u];                      \
    _Pragma("unroll")                                                         \
    for (int u = 0; u < 4; ++u) GS[u] = GS2[((unsigned)R[u].x & 0x7fffu) * 100u + j2]; \
    _Pragma("unroll")                                                         \
    for (int u = 0; u < 4; ++u) GR[u] = Rel2[((unsigned)R[u].x >> 15) * 100u + j2];    \
  }
#define COMPB(R, GS, GR)                                                      \
  {                                                                           \
    _Pragma("unroll")                                                         \
    for (int u = 0; u < 4; ++u) DO_EDGE(GS[u], GR[u], R[u].y)                 \
  }
  int cnt = e1 - e0;
  int nb = cnt >> 2;
  int2 rA[4], rB[4];
  uint2 gsA[4], grA[4], gsB[4], grB[4];
  if (nb > 0) LOADB(rA, gsA, grA, e0)
  int b = 1;
  for (; b + 1 < nb; b += 2) {
    LOADB(rB, gsB, grB, e0 + b * 4)
    COMPB(rA, gsA, grA)
    LOADB(rA, gsA, grA, e0 + (b + 1) * 4)
    COMPB(rB, gsB, grB)
  }
  if (b < nb) {
    LOADB(rB, gsB, grB, e0 + b * 4)
    COMPB(rA, gsA, grA)
    COMPB(rB, gsB, grB)
  } else if (nb > 0) {
    COMPB(rA, gsA, grA)
  }
  for (int i = e0 + nb * 4; i < e1; ++i) {
    int2 r = erec[i];
    uint2 g = GS2[((unsigned)r.x & 0x7fffu) * 100u + j2];
    uint2 R = Rel2[((unsigned)r.x >> 15) * 100u + j2];
    DO_EDGE(g, R, r.y)
  }
#undef COMPB
#undef LOADB
#undef DO_EDGE
  uint2 lp = GL2[(size_t)n * 100 + j2];
  float o0, o1;
  if (e1 > e0) {
    float nm = norm[n];
    o0 = (num0 / s0 + xd0) * nm + bf2f_lo(lp.x);
    o1 = (num1 / s1 + xd1) * nm + bf2f_lo(lp.y);
  } else {
    o0 = bf2f_hi(lp.x);
    o1 = bf2f_hi(lp.y);
  }
  ((float2*)(out + (size_t)n * DD))[j2] = make_float2(fmaxf(o0, 0.f), fmaxf(o1, 0.f));
}

extern "C" void kernel_launch(void* const* d_in, const int* in_sizes, int n_in,
                              void* d_out, int out_size, void* d_ws, size_t ws_size,
                              hipStream_t stream) {
  const float* node = (const float*)d_in[0];
  const float* rel  = (const float*)d_in[1];
  const float* norm = (const float*)d_in[2];
  const float* fre  = (const float*)d_in[3];
  const float* wt   = (const float*)d_in[4];
  const float* wq   = (const float*)d_in[5];
  const float* lw   = (const float*)d_in[6];
  const float* elw  = (const float*)d_in[7];
  const int* esrc = (const int*)d_in[8];
  const int* edst = (const int*)d_in[9];
  const int* etyp = (const int*)d_in[10];
  float* out = (float*)d_out;

  char* p = (char*)d_ws;
  auto carve = [&](size_t bytes) -> char* {
    char* r = p; p += (bytes + 255) & ~(size_t)255; return r;
  };
  unsigned short* A     = (unsigned short*)carve((size_t)(MT * 128) * KP * 2);
  unsigned short* Arel  = (unsigned short*)carve((size_t)RRR * KP * 2);
  unsigned short* BtAll = (unsigned short*)carve((size_t)(1280 + 512) * KP * 2);
  unsigned short* NT2   = (unsigned short*)carve((size_t)3 * NN * 400 * 2);
  unsigned short* RelP  = (unsigned short*)carve((size_t)RRR * 400 * 2);
  float* cq   = (float*)carve((size_t)DD * 4);
  int* degcur = (int*)carve((size_t)2 * NN * 4);     // deg | cursor
  int* offs   = (int*)carve((size_t)(NN + 1) * 4);
  int2* erec  = (int2*)carve((size_t)EE * 8);

  unsigned short* Bt    = BtAll;
  unsigned short* BtRel = BtAll + (size_t)1280 * KP;
  int* deg    = degcur;
  int* cursor = degcur + NN;

  const uint2* GS2 = (const uint2*)NT2;
  const uint2* GD2 = GS2 + (size_t)NN * 100;
  const uint2* GL2 = GS2 + (size_t)2 * NN * 100;

  hipMemsetAsync(degcur, 0, (size_t)2 * NN * 4, stream);
  kPrep<<<PB_PAD, 256, 0, stream>>>(node, rel, edst, wt, wq, lw, elw,
                                    (unsigned int*)A, (unsigned int*)Arel, deg, Bt, BtRel, cq);
  k_scan<<<1, 1024, 0, stream>>>(deg, offs);
  k_gs<<<NBLK_GEMM + NBLK_SCAT, 256, 0, stream>>>(A, Bt, NT2, Arel, BtRel, RelP,
                                                  esrc, edst, etyp, fre, offs, cursor, erec);
  k_agg<<<NN, 128, 0, stream>>>(GS2, GD2, GL2, (const uint2*)RelP, (const float2*)cq,
                                norm, offs, erec, out);
}